// Round 3
// baseline (17664.369 us; speedup 1.0000x reference)
//
#include <hip/hip_runtime.h>
#include <hip/hip_bf16.h>

using bf16 = __hip_bfloat16;

#define NS 20000
#define NE 640000
#define BN_EPS 1e-5f

__device__ __forceinline__ float bf2f(bf16 x) { return __bfloat162float(x); }
__device__ __forceinline__ bf16 f2bf(float x) { return __float2bfloat16(x); }
__device__ __forceinline__ float us2f(unsigned short u) { return __uint_as_float(((unsigned)u) << 16); }

__device__ __forceinline__ float4 load4f(const float* p) { return *reinterpret_cast<const float4*>(p); }
__device__ __forceinline__ void storeOut(float* p, float v) { *p = v; }
__device__ __forceinline__ void storeOut(bf16* p, float v) { *p = f2bf(v); }

// ---------------- conv1 stats: accumulate per-channel sum/sumsq of raw conv1 ----------------------
__global__ __launch_bounds__(256) void k_conv1_stats(const float* __restrict__ wav,
    const float* __restrict__ w1, const float* __restrict__ b1, float* __restrict__ stats)
{
  __shared__ float xs[192];
  __shared__ float ssum[32], ssq[32];
  int n = blockIdx.x, t = threadIdx.x;
  if (t < 187) xs[2 + t] = wav[n * 187 + t];
  else if (t == 187) { xs[0] = 0.f; xs[1] = 0.f; }
  else if (t == 188) { xs[189] = 0.f; xs[190] = 0.f; xs[191] = 0.f; }
  if (t < 32) { ssum[t] = 0.f; ssq[t] = 0.f; }
  __syncthreads();
  int c = t & 31, g = t >> 5;
  float wr[5];
#pragma unroll
  for (int k = 0; k < 5; ++k) wr[k] = w1[c * 5 + k];
  float bias = b1[c], s = 0.f, s2 = 0.f;
  for (int l = g; l < 187; l += 8) {
    float y = bias;
#pragma unroll
    for (int k = 0; k < 5; ++k) y = fmaf(xs[l + k], wr[k], y);
    s += y; s2 = fmaf(y, y, s2);
  }
  atomicAdd(&ssum[c], s); atomicAdd(&ssq[c], s2);
  __syncthreads();
  if (t < 32) { atomicAdd(&stats[t], ssum[t]); atomicAdd(&stats[128 + t], ssq[t]); }
}

// ---------------- BN finalize: sum@[0..C), sumsq@[128..128+C) -> scale@off, shift@off+128 ----------
__global__ void k_bn_finalize(float* __restrict__ stats, const float* __restrict__ g,
                              const float* __restrict__ b, int C, float invCnt, int off)
{
  int t = threadIdx.x;
  if (t < C) {
    float mean = stats[t] * invCnt;
    float var = stats[128 + t] * invCnt - mean * mean;
    float sc = g[t] * rsqrtf(var + BN_EPS);
    stats[off + t] = sc;
    stats[off + 128 + t] = b[t] - mean * sc;
  }
}

// ---------------- pass A: conv1 -> BN1 -> relu -> pool -> conv2 -> stats2 only ---------------------
__global__ __launch_bounds__(256) void k_s2stats(const float* __restrict__ wav,
    const float* __restrict__ w1, const float* __restrict__ b1,
    const float* __restrict__ sc1, const float* __restrict__ sh1,
    const float* __restrict__ w2, const float* __restrict__ b2,
    float* __restrict__ statacc)
{
  __shared__ float xs[192];
  __shared__ float p1[32 * 104];   // cols 0..1 & 95..103 zero; data at 2+lp, lp<93
  __shared__ float w2s[10240];
  __shared__ float ssum[64], ssq[64];
  int n = blockIdx.x, t = threadIdx.x;
  for (int i = t; i < 10240; i += 256) w2s[i] = w2[i];
  if (t < 187) xs[2 + t] = wav[n * 187 + t];
  else if (t == 187) { xs[0] = 0.f; xs[1] = 0.f; }
  else if (t == 188) { xs[189] = 0.f; xs[190] = 0.f; xs[191] = 0.f; }
  if (t < 64) { ssum[t] = 0.f; ssq[t] = 0.f; }
  if (t < 32) {
    p1[t * 104 + 0] = 0.f; p1[t * 104 + 1] = 0.f;
#pragma unroll
    for (int m = 95; m < 104; ++m) p1[t * 104 + m] = 0.f;
  }
  __syncthreads();
  {
    int c = t & 31, g = t >> 5;
    float wr[5];
#pragma unroll
    for (int k = 0; k < 5; ++k) wr[k] = w1[c * 5 + k];
    float bias = b1[c], sc = sc1[c], sh = sh1[c];
    for (int lp = g; lp < 93; lp += 8) {
      int b0 = 2 * lp;
      float y0 = bias, y1 = bias;
#pragma unroll
      for (int k = 0; k < 5; ++k) {
        y0 = fmaf(xs[b0 + k], wr[k], y0);
        y1 = fmaf(xs[b0 + 1 + k], wr[k], y1);
      }
      y0 = fmaf(y0, sc, sh); y1 = fmaf(y1, sc, sh);
      p1[c * 104 + 2 + lp] = fmaxf(fmaxf(y0, y1), 0.f);
    }
  }
  __syncthreads();
  int oc = (t & 15) * 4, l0 = (t >> 4) * 6;
  float acc[4][6] = {};
  for (int i = 0; i < 32; ++i) {
    float xv[10];
#pragma unroll
    for (int j = 0; j < 10; ++j) xv[j] = p1[i * 104 + l0 + j];
#pragma unroll
    for (int k = 0; k < 5; ++k) {
      float wa = w2s[(oc + 0) * 160 + i * 5 + k];
      float wb = w2s[(oc + 1) * 160 + i * 5 + k];
      float wc = w2s[(oc + 2) * 160 + i * 5 + k];
      float wd = w2s[(oc + 3) * 160 + i * 5 + k];
#pragma unroll
      for (int j = 0; j < 6; ++j) {
        acc[0][j] = fmaf(xv[j + k], wa, acc[0][j]);
        acc[1][j] = fmaf(xv[j + k], wb, acc[1][j]);
        acc[2][j] = fmaf(xv[j + k], wc, acc[2][j]);
        acc[3][j] = fmaf(xv[j + k], wd, acc[3][j]);
      }
    }
  }
#pragma unroll
  for (int c = 0; c < 4; ++c) {
    float bias = b2[oc + c], s = 0.f, s2 = 0.f;
#pragma unroll
    for (int j = 0; j < 6; ++j) {
      if (l0 + j < 93) {
        float y = acc[c][j] + bias;
        s += y; s2 = fmaf(y, y, s2);
      }
    }
    atomicAdd(&ssum[oc + c], s); atomicAdd(&ssq[oc + c], s2);
  }
  __syncthreads();
  if (t < 64) { atomicAdd(&statacc[t], ssum[t]); atomicAdd(&statacc[128 + t], ssq[t]); }
}

// ---------------- pass B: conv1->BN1->pool->conv2->BN2->pool->conv3 -> pooled-raw3 + stats3 --------
// Stores max(raw3[2p], raw3[2p+1]) (valid because BN3 gamma=1>0: pool commutes with BN+relu).
__global__ __launch_bounds__(256) void k_s123(const float* __restrict__ wav,
    const float* __restrict__ w1, const float* __restrict__ b1,
    const float* __restrict__ sc1, const float* __restrict__ sh1,
    const float* __restrict__ w2, const float* __restrict__ b2,
    const float* __restrict__ sc2, const float* __restrict__ sh2,
    const float* __restrict__ w3, const float* __restrict__ b3,
    bf16* __restrict__ praw3, float* __restrict__ statacc)
{
  __shared__ float xs[192];
  __shared__ float ssum[128], ssq[128];
  __shared__ __align__(16) char Rb[54272];
  float* p1  = (float*)Rb;            // [32][104] (phases 1-2)
  float* w2s = (float*)(Rb + 13312);  // [10240]   (phases 0-2)
  float* p2  = (float*)Rb;            // [64][52]  (phase 3; overlays p1)
  bf16*  w3s = (bf16*)(Rb + 13312);   // [20480]   (phase 3; overlays w2s)
  int n = blockIdx.x, t = threadIdx.x;
  for (int i = t; i < 10240; i += 256) w2s[i] = w2[i];
  if (t < 187) xs[2 + t] = wav[n * 187 + t];
  else if (t == 187) { xs[0] = 0.f; xs[1] = 0.f; }
  else if (t == 188) { xs[189] = 0.f; xs[190] = 0.f; xs[191] = 0.f; }
  if (t < 128) { ssum[t] = 0.f; ssq[t] = 0.f; }
  if (t < 32) {
    p1[t * 104 + 0] = 0.f; p1[t * 104 + 1] = 0.f;
#pragma unroll
    for (int m = 95; m < 104; ++m) p1[t * 104 + m] = 0.f;
  }
  __syncthreads();
  // conv1 -> BN1 -> relu -> pool -> p1
  {
    int c = t & 31, g = t >> 5;
    float wr[5];
#pragma unroll
    for (int k = 0; k < 5; ++k) wr[k] = w1[c * 5 + k];
    float bias = b1[c], sc = sc1[c], sh = sh1[c];
    for (int lp = g; lp < 93; lp += 8) {
      int b0 = 2 * lp;
      float y0 = bias, y1 = bias;
#pragma unroll
      for (int k = 0; k < 5; ++k) {
        y0 = fmaf(xs[b0 + k], wr[k], y0);
        y1 = fmaf(xs[b0 + 1 + k], wr[k], y1);
      }
      y0 = fmaf(y0, sc, sh); y1 = fmaf(y1, sc, sh);
      p1[c * 104 + 2 + lp] = fmaxf(fmaxf(y0, y1), 0.f);
    }
  }
  __syncthreads();
  // conv2 into regs
  int oc = (t & 15) * 4, g2 = t >> 4, l0 = g2 * 6;
  float acc[4][6] = {};
  for (int i = 0; i < 32; ++i) {
    float xv[10];
#pragma unroll
    for (int j = 0; j < 10; ++j) xv[j] = p1[i * 104 + l0 + j];
#pragma unroll
    for (int k = 0; k < 5; ++k) {
      float wa = w2s[(oc + 0) * 160 + i * 5 + k];
      float wb = w2s[(oc + 1) * 160 + i * 5 + k];
      float wc = w2s[(oc + 2) * 160 + i * 5 + k];
      float wd = w2s[(oc + 3) * 160 + i * 5 + k];
#pragma unroll
      for (int j = 0; j < 6; ++j) {
        acc[0][j] = fmaf(xv[j + k], wa, acc[0][j]);
        acc[1][j] = fmaf(xv[j + k], wb, acc[1][j]);
        acc[2][j] = fmaf(xv[j + k], wc, acc[2][j]);
        acc[3][j] = fmaf(xv[j + k], wd, acc[3][j]);
      }
    }
  }
  __syncthreads();   // all reads of p1/w2s complete; region reused as p2/w3s below
  // BN2(final)+relu+pool -> p2
#pragma unroll
  for (int c = 0; c < 4; ++c) {
    int ch = oc + c;
    float bias = b2[ch], sc = sc2[ch], sh = sh2[ch];
#pragma unroll
    for (int u = 0; u < 3; ++u) {
      int pp = 3 * g2 + u;
      if (pp < 46) {
        float ya = fmaf(acc[c][2 * u] + bias, sc, sh);
        float yb = fmaf(acc[c][2 * u + 1] + bias, sc, sh);
        p2[ch * 52 + 2 + pp] = fmaxf(fmaxf(ya, yb), 0.f);
      }
    }
  }
  if (t < 64) {
    p2[t * 52 + 0] = 0.f; p2[t * 52 + 1] = 0.f;
    p2[t * 52 + 48] = 0.f; p2[t * 52 + 49] = 0.f; p2[t * 52 + 50] = 0.f; p2[t * 52 + 51] = 0.f;
  }
  // conv3 in 2 halves of output channels
  for (int h = 0; h < 2; ++h) {
    __syncthreads();
    for (int i = t; i < 20480; i += 256) w3s[i] = f2bf(w3[h * 20480 + i]);
    __syncthreads();
    int oc2 = (t & 31) * 2, gb = t >> 5, l0b = gb * 6;
    float a2[2][6] = {};
    for (int i = 0; i < 64; ++i) {
      float xv[10];
#pragma unroll
      for (int j = 0; j < 10; ++j) xv[j] = p2[i * 52 + l0b + j];
#pragma unroll
      for (int k = 0; k < 5; ++k) {
        float wa = bf2f(w3s[(oc2 + 0) * 320 + i * 5 + k]);
        float wb = bf2f(w3s[(oc2 + 1) * 320 + i * 5 + k]);
#pragma unroll
        for (int j = 0; j < 6; ++j) {
          a2[0][j] = fmaf(xv[j + k], wa, a2[0][j]);
          a2[1][j] = fmaf(xv[j + k], wb, a2[1][j]);
        }
      }
    }
#pragma unroll
    for (int c = 0; c < 2; ++c) {
      int ch = h * 64 + oc2 + c;
      float bias3 = b3[ch], s = 0.f, s2 = 0.f;
      float yv[6];
#pragma unroll
      for (int j = 0; j < 6; ++j) {
        yv[j] = a2[c][j] + bias3;
        if (l0b + j < 46) { s += yv[j]; s2 = fmaf(yv[j], yv[j], s2); }
      }
#pragma unroll
      for (int u = 0; u < 3; ++u) {
        int pp = 3 * gb + u;
        if (pp < 23) praw3[(size_t)n * 2944 + ch * 23 + pp] = f2bf(fmaxf(yv[2 * u], yv[2 * u + 1]));
      }
      atomicAdd(&ssum[ch], s); atomicAdd(&ssq[ch], s2);
    }
  }
  __syncthreads();
  if (t < 128) { atomicAdd(&statacc[t], ssum[t]); atomicAdd(&statacc[128 + t], ssq[t]); }
}

// ---------------- efc1 GEMM with fused BN3+relu on pooled-raw A ------------------------------------
__global__ __launch_bounds__(256) void k_efc1(const bf16* __restrict__ praw,
    const float* __restrict__ sc3, const float* __restrict__ sh3,
    const float* __restrict__ W, const float* __restrict__ bias, float* __restrict__ C)
{
  const int M = NS, K = 2944, O = 256;
  __shared__ float As[16][68];
  __shared__ float Bs[16][68];
  __shared__ float scs[128], shs[128];
  int tid = threadIdx.x;
  if (tid < 128) { scs[tid] = sc3[tid]; shs[tid] = sh3[tid]; }
  __syncthreads();
  int bm = blockIdx.x * 64, bo = blockIdx.y * 64;
  int lr = tid >> 2, lk = (tid & 3) * 4;
  int tm = (tid & 15) * 4, to = (tid >> 4) * 4;
  float acc[4][4] = {};
  for (int k0 = 0; k0 < K; k0 += 16) {
    float a0 = 0.f, a1 = 0.f, a2 = 0.f, a3 = 0.f;
    float4 wv = make_float4(0.f, 0.f, 0.f, 0.f);
    int arow = bm + lr;
    if (arow < M) {
      int kb = k0 + lk;
      ushort4 u4 = *reinterpret_cast<const ushort4*>(praw + (size_t)arow * K + kb);
      int c0 = (kb + 0) / 23, c1 = (kb + 1) / 23, c2 = (kb + 2) / 23, c3 = (kb + 3) / 23;
      a0 = fmaxf(fmaf(us2f(u4.x), scs[c0], shs[c0]), 0.f);
      a1 = fmaxf(fmaf(us2f(u4.y), scs[c1], shs[c1]), 0.f);
      a2 = fmaxf(fmaf(us2f(u4.z), scs[c2], shs[c2]), 0.f);
      a3 = fmaxf(fmaf(us2f(u4.w), scs[c3], shs[c3]), 0.f);
    }
    int orow = bo + lr;
    if (orow < O) wv = load4f(W + (size_t)orow * K + k0 + lk);
    As[lk + 0][lr] = a0; As[lk + 1][lr] = a1; As[lk + 2][lr] = a2; As[lk + 3][lr] = a3;
    Bs[lk + 0][lr] = wv.x; Bs[lk + 1][lr] = wv.y; Bs[lk + 2][lr] = wv.z; Bs[lk + 3][lr] = wv.w;
    __syncthreads();
#pragma unroll
    for (int k = 0; k < 16; ++k) {
      const float4 a = *reinterpret_cast<const float4*>(&As[k][tm]);
      const float4 b = *reinterpret_cast<const float4*>(&Bs[k][to]);
      float a4[4] = {a.x, a.y, a.z, a.w};
      float b4[4] = {b.x, b.y, b.z, b.w};
#pragma unroll
      for (int i = 0; i < 4; ++i)
#pragma unroll
        for (int j = 0; j < 4; ++j) acc[i][j] = fmaf(a4[i], b4[j], acc[i][j]);
    }
    __syncthreads();
  }
#pragma unroll
  for (int i = 0; i < 4; ++i) {
    int row = bm + tm + i;
    if (row >= M) continue;
#pragma unroll
    for (int j = 0; j < 4; ++j) {
      int col = bo + to + j;
      float v = acc[i][j] + bias[col];
      C[(size_t)row * O + col] = fmaxf(v, 0.f);
    }
  }
}

// ---------------- Generic tiled GEMM: C[m,o] = act( sum_k A[m,k]*W[o,k] (+bias[o]) (*rscale[m]) ) --
template <typename OT, bool RELU, bool RSCALE>
__global__ __launch_bounds__(256) void k_gemm(const float* __restrict__ A, const float* __restrict__ W,
    const float* __restrict__ bias, const float* __restrict__ rscale,
    OT* __restrict__ C, int M, int K, int O)
{
  __shared__ float As[16][68];
  __shared__ float Bs[16][68];
  int tid = threadIdx.x;
  int bm = blockIdx.x * 64, bo = blockIdx.y * 64;
  int lr = tid >> 2, lk = (tid & 3) * 4;
  int tm = (tid & 15) * 4, to = (tid >> 4) * 4;
  float acc[4][4] = {};
  for (int k0 = 0; k0 < K; k0 += 16) {
    float4 av = make_float4(0.f, 0.f, 0.f, 0.f);
    float4 wv = make_float4(0.f, 0.f, 0.f, 0.f);
    int arow = bm + lr;
    if (arow < M) av = load4f(A + (size_t)arow * K + k0 + lk);
    int orow = bo + lr;
    if (orow < O) wv = load4f(W + (size_t)orow * K + k0 + lk);
    As[lk + 0][lr] = av.x; As[lk + 1][lr] = av.y; As[lk + 2][lr] = av.z; As[lk + 3][lr] = av.w;
    Bs[lk + 0][lr] = wv.x; Bs[lk + 1][lr] = wv.y; Bs[lk + 2][lr] = wv.z; Bs[lk + 3][lr] = wv.w;
    __syncthreads();
#pragma unroll
    for (int k = 0; k < 16; ++k) {
      const float4 a = *reinterpret_cast<const float4*>(&As[k][tm]);
      const float4 b = *reinterpret_cast<const float4*>(&Bs[k][to]);
      float a4[4] = {a.x, a.y, a.z, a.w};
      float b4[4] = {b.x, b.y, b.z, b.w};
#pragma unroll
      for (int i = 0; i < 4; ++i)
#pragma unroll
        for (int j = 0; j < 4; ++j) acc[i][j] = fmaf(a4[i], b4[j], acc[i][j]);
    }
    __syncthreads();
  }
#pragma unroll
  for (int i = 0; i < 4; ++i) {
    int row = bm + tm + i;
    if (row >= M) continue;
    float rs = RSCALE ? rscale[row] : 1.f;
#pragma unroll
    for (int j = 0; j < 4; ++j) {
      int col = bo + to + j;
      if (col >= O) continue;
      float v = acc[i][j];
      if (bias) v += bias[col];
      if (RSCALE) v *= rs;
      if (RELU) v = fmaxf(v, 0.f);
      storeOut(&C[(size_t)row * O + col], v);
    }
  }
}

// ---------------- GCN helpers ----------------------------------------------------------------------
__global__ void k_fill1(float* __restrict__ p, int n)
{
  int i = blockIdx.x * 256 + threadIdx.x;
  if (i < n) p[i] = 1.f;
}
__global__ void k_degacc(const int* __restrict__ dst, float* __restrict__ deg)
{
  int e = blockIdx.x * 256 + threadIdx.x;
  if (e < NE) atomicAdd(&deg[dst[e]], 1.f);
}
__global__ void k_dinv(float* __restrict__ deg)
{
  int i = blockIdx.x * 256 + threadIdx.x;
  if (i < NS) deg[i] = rsqrtf(fmaxf(deg[i], 1e-12f));
}
__global__ __launch_bounds__(256) void k_scatter(const int* __restrict__ src, const int* __restrict__ dst,
    const float* __restrict__ hs, float* __restrict__ agg)
{
  int tid = blockIdx.x * 256 + threadIdx.x;
  if (tid >= NE * 32) return;
  int e = tid >> 5, q = tid & 31;
  int s = src[e], d = dst[e];
  float4 v = reinterpret_cast<const float4*>(hs)[(size_t)s * 32 + q];
  float* o = agg + (size_t)d * 128 + q * 4;
  atomicAdd(o + 0, v.x); atomicAdd(o + 1, v.y); atomicAdd(o + 2, v.z); atomicAdd(o + 3, v.w);
}
__global__ void k_gcn_post(const float* __restrict__ agg, const float* __restrict__ hs,
    const float* __restrict__ dinv, const float* __restrict__ b, float* __restrict__ out, int relu)
{
  int total = NS * 128;
  for (int i = blockIdx.x * 256 + threadIdx.x; i < total; i += gridDim.x * 256) {
    int n = i >> 7, f = i & 127;
    float v = (agg[i] + hs[i]) * dinv[n] + b[f];
    if (relu) v = fmaxf(v, 0.f);
    out[i] = v;
  }
}

// ---------------- decoder input concat: [z | cls_emb[label]] ---------------------------------------
__global__ void k_dcat(const float* __restrict__ z, const int* __restrict__ labels,
    const float* __restrict__ emb, float* __restrict__ dcat)
{
  int total = NS * 160;
  for (int i = blockIdx.x * 256 + threadIdx.x; i < total; i += gridDim.x * 256) {
    int n = i / 160, f = i % 160;
    dcat[i] = (f < 128) ? z[(size_t)n * 128 + f] : emb[labels[n] * 32 + (f - 128)];
  }
}

// ---------------- convT1: (N,128,23)->(N,64,46), stride2 pad1 K4, + stats --------------------------
__global__ __launch_bounds__(256) void k_convT1(const bf16* __restrict__ d2,
    const float* __restrict__ w, const float* __restrict__ b,
    bf16* __restrict__ raw, float* __restrict__ stats)
{
  __shared__ float xsh[2944];     // [128][23]
  __shared__ bf16 wsh[16384];     // half of (128,64,4) by input channel
  __shared__ float ssum[64], ssq[64];
  int n = blockIdx.x, t = threadIdx.x;
  for (int i = t; i < 2944; i += 256) xsh[i] = bf2f(d2[(size_t)n * 2944 + i]);
  if (t < 64) { ssum[t] = 0.f; ssq[t] = 0.f; }
  int o = t & 63, g = t >> 6;     // g 0..3 -> positions 12g..12g+11
  float acc[12] = {};
  for (int half = 0; half < 2; ++half) {
    __syncthreads();
    for (int i = t; i < 16384; i += 256) wsh[i] = f2bf(w[half * 16384 + i]);
    __syncthreads();
    for (int i = 0; i < 64; ++i) {
      int ci = half * 64 + i;
      float w0 = bf2f(wsh[i * 256 + o * 4 + 0]);
      float w1 = bf2f(wsh[i * 256 + o * 4 + 1]);
      float w2 = bf2f(wsh[i * 256 + o * 4 + 2]);
      float w3 = bf2f(wsh[i * 256 + o * 4 + 3]);
      float xl[8];
#pragma unroll
      for (int m = 0; m < 8; ++m) {
        int l = 6 * g - 1 + m;
        xl[m] = (l >= 0 && l < 23) ? xsh[ci * 23 + l] : 0.f;
      }
#pragma unroll
      for (int j = 0; j < 12; ++j) {
        if (j & 1) acc[j] = fmaf(w0, xl[(j + 1) / 2 + 1], fmaf(w2, xl[(j + 1) / 2], acc[j]));
        else       acc[j] = fmaf(w1, xl[j / 2 + 1],       fmaf(w3, xl[j / 2],       acc[j]));
      }
    }
  }
  float bias = b[o], s = 0.f, s2 = 0.f;
  size_t base = (size_t)n * 2944;   // 64*46
#pragma unroll
  for (int j = 0; j < 12; ++j) {
    int tp = 12 * g + j;
    if (tp < 46) {
      float y = acc[j] + bias;
      raw[base + (size_t)o * 46 + tp] = f2bf(y);
      s += y; s2 = fmaf(y, y, s2);
    }
  }
  atomicAdd(&ssum[o], s); atomicAdd(&ssq[o], s2);
  __syncthreads();
  if (t < 64) { atomicAdd(&stats[t], ssum[t]); atomicAdd(&stats[128 + t], ssq[t]); }
}

// ---------------- convT2: (BN1d+relu on raw1) -> (N,32,92), + stats --------------------------------
__global__ __launch_bounds__(256) void k_convT2(const bf16* __restrict__ raw1,
    const float* __restrict__ sc, const float* __restrict__ sh,
    const float* __restrict__ w, const float* __restrict__ b,
    bf16* __restrict__ raw2out, float* __restrict__ stats)
{
  __shared__ float xsh[2944];     // [64][46]
  __shared__ float wsh[8192];     // (64,32,4)
  __shared__ float ssum[32], ssq[32];
  int n = blockIdx.x, t = threadIdx.x;
  for (int i = t; i < 8192; i += 256) wsh[i] = w[i];
  for (int i = t; i < 2944; i += 256) {
    int c = i / 46;
    float v = fmaf(bf2f(raw1[(size_t)n * 2944 + i]), sc[c], sh[c]);
    xsh[i] = fmaxf(v, 0.f);
  }
  if (t < 32) { ssum[t] = 0.f; ssq[t] = 0.f; }
  __syncthreads();
  int o = t & 31, g = t >> 5;     // 8 groups x 12 positions (92 valid)
  float acc[12] = {};
  for (int i = 0; i < 64; ++i) {
    float w0 = wsh[i * 128 + o * 4 + 0];
    float w1 = wsh[i * 128 + o * 4 + 1];
    float w2 = wsh[i * 128 + o * 4 + 2];
    float w3 = wsh[i * 128 + o * 4 + 3];
    float xl[8];
#pragma unroll
    for (int m = 0; m < 8; ++m) {
      int l = 6 * g - 1 + m;
      xl[m] = (l >= 0 && l < 46) ? xsh[i * 46 + l] : 0.f;
    }
#pragma unroll
    for (int j = 0; j < 12; ++j) {
      if (j & 1) acc[j] = fmaf(w0, xl[(j + 1) / 2 + 1], fmaf(w2, xl[(j + 1) / 2], acc[j]));
      else       acc[j] = fmaf(w1, xl[j / 2 + 1],       fmaf(w3, xl[j / 2],       acc[j]));
    }
  }
  float bias = b[o], s = 0.f, s2 = 0.f;
  size_t base = (size_t)n * 2944;   // 32*92
#pragma unroll
  for (int j = 0; j < 12; ++j) {
    int tp = 12 * g + j;
    if (tp < 92) {
      float y = acc[j] + bias;
      raw2out[base + (size_t)o * 92 + tp] = f2bf(y);
      s += y; s2 = fmaf(y, y, s2);
    }
  }
  atomicAdd(&ssum[o], s); atomicAdd(&ssq[o], s2);
  __syncthreads();
  if (t < 32) { atomicAdd(&stats[t], ssum[t]); atomicAdd(&stats[128 + t], ssq[t]); }
}

// ---------------- convT3: (BN2d+relu on raw2) -> (N,1,184) -> recon padded to 187 ------------------
__global__ __launch_bounds__(256) void k_convT3(const bf16* __restrict__ raw2,
    const float* __restrict__ sc, const float* __restrict__ sh,
    const float* __restrict__ w, const float* __restrict__ b,
    float* __restrict__ recon)
{
  __shared__ float xsh[2944];   // [32][92]
  __shared__ float wsh[128];
  int n = blockIdx.x, t = threadIdx.x;
  if (t < 128) wsh[t] = w[t];
  for (int i = t; i < 2944; i += 256) {
    int c = i / 92;
    float v = fmaf(bf2f(raw2[(size_t)n * 2944 + i]), sc[c], sh[c]);
    xsh[i] = fmaxf(v, 0.f);
  }
  __syncthreads();
  if (t < 187) {
    float y = 0.f;
    if (t < 184) {
      y = b[0];
      if (t & 1) {
        int l1 = (t + 1) / 2, l2 = (t - 1) / 2;
        for (int i = 0; i < 32; ++i) {
          float a0 = (l1 < 92) ? wsh[i * 4 + 0] * xsh[i * 92 + l1] : 0.f;
          y += a0 + wsh[i * 4 + 2] * xsh[i * 92 + l2];
        }
      } else {
        int l1 = t / 2, l2 = t / 2 - 1;
        for (int i = 0; i < 32; ++i) {
          float a3 = (l2 >= 0) ? wsh[i * 4 + 3] * xsh[i * 92 + l2] : 0.f;
          y += wsh[i * 4 + 1] * xsh[i * 92 + l1] + a3;
        }
      }
    }
    recon[(size_t)n * 187 + t] = y;
  }
}

// ===================================================================================================
extern "C" void kernel_launch(void* const* d_in, const int* in_sizes, int n_in,
                              void* d_out, int out_size, void* d_ws, size_t ws_size,
                              hipStream_t stream)
{
  const float* wav    = (const float*)d_in[0];
  const int*   edges  = (const int*)d_in[1];     // [0..E)=src, [E..2E)=dst (int32)
  const int*   labels = (const int*)d_in[2];
  int a = 3;
  const float* ec1_w = (const float*)d_in[a++]; const float* ec1_b = (const float*)d_in[a++];
  const float* bn1e_g = (const float*)d_in[a++]; const float* bn1e_b = (const float*)d_in[a++];
  const float* ec2_w = (const float*)d_in[a++]; const float* ec2_b = (const float*)d_in[a++];
  const float* bn2e_g = (const float*)d_in[a++]; const float* bn2e_b = (const float*)d_in[a++];
  const float* ec3_w = (const float*)d_in[a++]; const float* ec3_b = (const float*)d_in[a++];
  const float* bn3e_g = (const float*)d_in[a++]; const float* bn3e_b = (const float*)d_in[a++];
  const float* efc1_w = (const float*)d_in[a++]; const float* efc1_b = (const float*)d_in[a++];
  const float* efc2_w = (const float*)d_in[a++]; const float* efc2_b = (const float*)d_in[a++];
  const float* g1_w = (const float*)d_in[a++]; const float* g1_b = (const float*)d_in[a++];
  const float* g2_w = (const float*)d_in[a++]; const float* g2_b = (const float*)d_in[a++];
  const float* c1_w = (const float*)d_in[a++]; const float* c1_b = (const float*)d_in[a++];
  const float* c2_w = (const float*)d_in[a++]; const float* c2_b = (const float*)d_in[a++];
  const float* cls_emb = (const float*)d_in[a++];
  const float* dfc1_w = (const float*)d_in[a++]; const float* dfc1_b = (const float*)d_in[a++];
  const float* dfc2_w = (const float*)d_in[a++]; const float* dfc2_b = (const float*)d_in[a++];
  const float* dc1_w = (const float*)d_in[a++]; const float* dc1_b = (const float*)d_in[a++];
  const float* bn1d_g = (const float*)d_in[a++]; const float* bn1d_b = (const float*)d_in[a++];
  const float* dc2_w = (const float*)d_in[a++]; const float* dc2_b = (const float*)d_in[a++];
  const float* bn2d_g = (const float*)d_in[a++]; const float* bn2d_b = (const float*)d_in[a++];
  const float* dc3_w = (const float*)d_in[a++]; const float* dc3_b = (const float*)d_in[a++];

  // workspace layout — total 235,524,096 bytes
  char* ws = (char*)d_ws;
  bf16*  B1 = (bf16*)(ws + 0);               // 58,880,000 bf16: praw3 -> d2 -> raw2out
  bf16*  B2 = (bf16*)(ws + 117760000ULL);    // 58,880,000 bf16: (GCN floats below) -> raw1
  float* E1 = (float*)(ws + 117760000ULL);   // (N,256)
  float* FE = (float*)(ws + 138240000ULL);   // (N,128)
  float* LN = (float*)(ws + 148480000ULL);   // (N,128)
  float* AG = (float*)(ws + 158720000ULL);   // (N,128)
  float* DI = (float*)(ws + 168960000ULL);   // (N)
  float* DC = (float*)(ws + 169040000ULL);   // (N,160) ends at 181,840,000
  float* ST = (float*)(ws + 235520000ULL);   // 1024 floats: sums + 3x scale/shift slots

  float* zout   = (float*)d_out;             // (N,128)
  float* recon  = (float*)d_out + 2560000;   // (N,187)
  float* logits = (float*)d_out + 6300000;   // (N,5)

  // ---- encoder ----
  (void)hipMemsetAsync(ST, 0, 1024, stream);
  k_conv1_stats<<<NS, 256, 0, stream>>>(wav, ec1_w, ec1_b, ST);
  k_bn_finalize<<<1, 128, 0, stream>>>(ST, bn1e_g, bn1e_b, 32, 1.f / (NS * 187.f), 256);
  (void)hipMemsetAsync(ST, 0, 1024, stream);
  k_s2stats<<<NS, 256, 0, stream>>>(wav, ec1_w, ec1_b, ST + 256, ST + 384, ec2_w, ec2_b, ST);
  k_bn_finalize<<<1, 128, 0, stream>>>(ST, bn2e_g, bn2e_b, 64, 1.f / (NS * 93.f), 512);
  (void)hipMemsetAsync(ST, 0, 1024, stream);
  k_s123<<<NS, 256, 0, stream>>>(wav, ec1_w, ec1_b, ST + 256, ST + 384, ec2_w, ec2_b,
                                 ST + 512, ST + 640, ec3_w, ec3_b, B1, ST);
  k_bn_finalize<<<1, 128, 0, stream>>>(ST, bn3e_g, bn3e_b, 128, 1.f / (NS * 46.f), 768);
  k_efc1<<<dim3(313, 4), 256, 0, stream>>>(B1, ST + 768, ST + 896, efc1_w, efc1_b, E1);
  k_gemm<float, false, false><<<dim3(313, 2), 256, 0, stream>>>(E1, efc2_w, efc2_b, nullptr, FE, NS, 256, 128);

  // ---- GCN ----
  k_fill1<<<79, 256, 0, stream>>>(DI, NS);
  k_degacc<<<2500, 256, 0, stream>>>(edges + NE, DI);
  k_dinv<<<79, 256, 0, stream>>>(DI);
  k_gemm<float, false, true><<<dim3(313, 2), 256, 0, stream>>>(FE, g1_w, nullptr, DI, LN, NS, 128, 128);
  (void)hipMemsetAsync(AG, 0, (size_t)NS * 128 * 4, stream);
  k_scatter<<<80000, 256, 0, stream>>>(edges, edges + NE, LN, AG);
  k_gcn_post<<<2560, 256, 0, stream>>>(AG, LN, DI, g1_b, FE, 1);   // h -> FE
  k_gemm<float, false, true><<<dim3(313, 2), 256, 0, stream>>>(FE, g2_w, nullptr, DI, LN, NS, 128, 128);
  (void)hipMemsetAsync(AG, 0, (size_t)NS * 128 * 4, stream);
  k_scatter<<<80000, 256, 0, stream>>>(edges, edges + NE, LN, AG);
  k_gcn_post<<<2560, 256, 0, stream>>>(AG, LN, DI, g2_b, zout, 0); // z -> d_out

  // ---- classifier ----
  k_gemm<float, true, false><<<dim3(313, 1), 256, 0, stream>>>(zout, c1_w, c1_b, nullptr, AG, NS, 128, 64);
  k_gemm<float, false, false><<<dim3(313, 1), 256, 0, stream>>>(AG, c2_w, c2_b, nullptr, logits, NS, 64, 5);

  // ---- decoder ----
  k_dcat<<<4096, 256, 0, stream>>>(zout, labels, cls_emb, DC);
  k_gemm<float, true, false><<<dim3(313, 4), 256, 0, stream>>>(DC, dfc1_w, dfc1_b, nullptr, E1, NS, 160, 256);
  k_gemm<bf16, true, false><<<dim3(313, 46), 256, 0, stream>>>(E1, dfc2_w, dfc2_b, nullptr, B1, NS, 256, 2944);
  (void)hipMemsetAsync(ST, 0, 1024, stream);
  k_convT1<<<NS, 256, 0, stream>>>(B1, dc1_w, dc1_b, B2, ST);
  k_bn_finalize<<<1, 128, 0, stream>>>(ST, bn1d_g, bn1d_b, 64, 1.f / (NS * 46.f), 256);
  (void)hipMemsetAsync(ST, 0, 1024, stream);
  k_convT2<<<NS, 256, 0, stream>>>(B2, ST + 256, ST + 384, dc2_w, dc2_b, B1, ST);
  k_bn_finalize<<<1, 128, 0, stream>>>(ST, bn2d_g, bn2d_b, 32, 1.f / (NS * 92.f), 512);
  k_convT3<<<NS, 256, 0, stream>>>(B1, ST + 512, ST + 640, dc3_w, dc3_b, recon);
}

// Round 4
// 9512.666 us; speedup vs baseline: 1.8569x; 1.8569x over previous
//
#include <hip/hip_runtime.h>
#include <hip/hip_bf16.h>

using bf16 = __hip_bfloat16;

#define NS 20000
#define NE 640000
#define BN_EPS 1e-5f

__device__ __forceinline__ float bf2f(bf16 x) { return __bfloat162float(x); }
__device__ __forceinline__ bf16 f2bf(float x) { return __float2bfloat16(x); }
__device__ __forceinline__ float us2f(unsigned short u) { return __uint_as_float(((unsigned)u) << 16); }

__device__ __forceinline__ float4 load4f(const float* p) { return *reinterpret_cast<const float4*>(p); }
__device__ __forceinline__ void storeOut(float* p, float v) { *p = v; }
__device__ __forceinline__ void storeOut(bf16* p, float v) { *p = f2bf(v); }

// ---------------- conv1 stats: accumulate per-channel sum/sumsq of raw conv1 ----------------------
__global__ __launch_bounds__(256) void k_conv1_stats(const float* __restrict__ wav,
    const float* __restrict__ w1, const float* __restrict__ b1, float* __restrict__ stats)
{
  __shared__ float xs[192];
  __shared__ float ssum[32], ssq[32];
  int n = blockIdx.x, t = threadIdx.x;
  if (t < 187) xs[2 + t] = wav[n * 187 + t];
  else if (t == 187) { xs[0] = 0.f; xs[1] = 0.f; }
  else if (t == 188) { xs[189] = 0.f; xs[190] = 0.f; xs[191] = 0.f; }
  if (t < 32) { ssum[t] = 0.f; ssq[t] = 0.f; }
  __syncthreads();
  int c = t & 31, g = t >> 5;
  float wr[5];
#pragma unroll
  for (int k = 0; k < 5; ++k) wr[k] = w1[c * 5 + k];
  float bias = b1[c], s = 0.f, s2 = 0.f;
  for (int l = g; l < 187; l += 8) {
    float y = bias;
#pragma unroll
    for (int k = 0; k < 5; ++k) y = fmaf(xs[l + k], wr[k], y);
    s += y; s2 = fmaf(y, y, s2);
  }
  atomicAdd(&ssum[c], s); atomicAdd(&ssq[c], s2);
  __syncthreads();
  if (t < 32) { atomicAdd(&stats[t], ssum[t]); atomicAdd(&stats[128 + t], ssq[t]); }
}

// ---------------- BN finalize: sum@[0..C), sumsq@[128..128+C) -> scale@off, shift@off+128 ----------
__global__ void k_bn_finalize(float* __restrict__ stats, const float* __restrict__ g,
                              const float* __restrict__ b, int C, float invCnt, int off)
{
  int t = threadIdx.x;
  if (t < C) {
    float mean = stats[t] * invCnt;
    float var = stats[128 + t] * invCnt - mean * mean;
    float sc = g[t] * rsqrtf(var + BN_EPS);
    stats[off + t] = sc;
    stats[off + 128 + t] = b[t] - mean * sc;
  }
}

// ---------------- pass A: conv1 -> BN1 -> relu -> pool -> conv2 -> stats2 only ---------------------
// w2t in LDS is TRANSPOSED [tap(160)][oc(64)] so lanes (varying oc) read consecutive banks.
__global__ __launch_bounds__(256) void k_s2stats(const float* __restrict__ wav,
    const float* __restrict__ w1, const float* __restrict__ b1,
    const float* __restrict__ sc1, const float* __restrict__ sh1,
    const float* __restrict__ w2, const float* __restrict__ b2,
    float* __restrict__ statacc)
{
  __shared__ float xs[192];
  __shared__ float p1[32 * 104];   // cols 0..1 & 95..103 zero; data at 2+lp, lp<93
  __shared__ __align__(16) float w2t[10240];   // [160][64]
  __shared__ float ssum[64], ssq[64];
  int n = blockIdx.x, t = threadIdx.x;
  for (int i = t; i < 10240; i += 256) w2t[(i % 160) * 64 + (i / 160)] = w2[i];
  if (t < 187) xs[2 + t] = wav[n * 187 + t];
  else if (t == 187) { xs[0] = 0.f; xs[1] = 0.f; }
  else if (t == 188) { xs[189] = 0.f; xs[190] = 0.f; xs[191] = 0.f; }
  if (t < 64) { ssum[t] = 0.f; ssq[t] = 0.f; }
  if (t < 32) {
    p1[t * 104 + 0] = 0.f; p1[t * 104 + 1] = 0.f;
#pragma unroll
    for (int m = 95; m < 104; ++m) p1[t * 104 + m] = 0.f;
  }
  __syncthreads();
  {
    int c = t & 31, g = t >> 5;
    float wr[5];
#pragma unroll
    for (int k = 0; k < 5; ++k) wr[k] = w1[c * 5 + k];
    float bias = b1[c], sc = sc1[c], sh = sh1[c];
    for (int lp = g; lp < 93; lp += 8) {
      int b0 = 2 * lp;
      float y0 = bias, y1 = bias;
#pragma unroll
      for (int k = 0; k < 5; ++k) {
        y0 = fmaf(xs[b0 + k], wr[k], y0);
        y1 = fmaf(xs[b0 + 1 + k], wr[k], y1);
      }
      y0 = fmaf(y0, sc, sh); y1 = fmaf(y1, sc, sh);
      p1[c * 104 + 2 + lp] = fmaxf(fmaxf(y0, y1), 0.f);
    }
  }
  __syncthreads();
  int oc = (t & 15) * 4, l0 = (t >> 4) * 6;
  float acc[4][6] = {};
  for (int i = 0; i < 32; ++i) {
    float xv[10];
#pragma unroll
    for (int j = 0; j < 10; ++j) xv[j] = p1[i * 104 + l0 + j];
#pragma unroll
    for (int k = 0; k < 5; ++k) {
      const float4 wv = *reinterpret_cast<const float4*>(&w2t[(i * 5 + k) * 64 + oc]);
#pragma unroll
      for (int j = 0; j < 6; ++j) {
        acc[0][j] = fmaf(xv[j + k], wv.x, acc[0][j]);
        acc[1][j] = fmaf(xv[j + k], wv.y, acc[1][j]);
        acc[2][j] = fmaf(xv[j + k], wv.z, acc[2][j]);
        acc[3][j] = fmaf(xv[j + k], wv.w, acc[3][j]);
      }
    }
  }
#pragma unroll
  for (int c = 0; c < 4; ++c) {
    float bias = b2[oc + c], s = 0.f, s2 = 0.f;
#pragma unroll
    for (int j = 0; j < 6; ++j) {
      if (l0 + j < 93) {
        float y = acc[c][j] + bias;
        s += y; s2 = fmaf(y, y, s2);
      }
    }
    atomicAdd(&ssum[oc + c], s); atomicAdd(&ssq[oc + c], s2);
  }
  __syncthreads();
  if (t < 64) { atomicAdd(&statacc[t], ssum[t]); atomicAdd(&statacc[128 + t], ssq[t]); }
}

// ---------------- pass B: conv1->BN1->pool->conv2->BN2->pool->conv3 -> pooled-raw3 + stats3 --------
// Stores max(raw3[2p], raw3[2p+1]) (valid because BN3 gamma=1>0: pool commutes with BN+relu).
// Weight tiles in LDS are TRANSPOSED [tap][oc] for conflict-free lane access.
__global__ __launch_bounds__(256) void k_s123(const float* __restrict__ wav,
    const float* __restrict__ w1, const float* __restrict__ b1,
    const float* __restrict__ sc1, const float* __restrict__ sh1,
    const float* __restrict__ w2, const float* __restrict__ b2,
    const float* __restrict__ sc2, const float* __restrict__ sh2,
    const float* __restrict__ w3, const float* __restrict__ b3,
    bf16* __restrict__ praw3, float* __restrict__ statacc)
{
  __shared__ float xs[192];
  __shared__ float ssum[128], ssq[128];
  __shared__ __align__(16) char Rb[54272];
  float* p1  = (float*)Rb;            // [32][104] (phases 1-2)
  float* w2t = (float*)(Rb + 13312);  // [160][64] (phases 0-2)
  float* p2  = (float*)Rb;            // [64][52]  (phase 3; overlays p1)
  bf16*  w3t = (bf16*)(Rb + 13312);   // [320][64] per half (phase 3; overlays w2t)
  int n = blockIdx.x, t = threadIdx.x;
  for (int i = t; i < 10240; i += 256) w2t[(i % 160) * 64 + (i / 160)] = w2[i];
  if (t < 187) xs[2 + t] = wav[n * 187 + t];
  else if (t == 187) { xs[0] = 0.f; xs[1] = 0.f; }
  else if (t == 188) { xs[189] = 0.f; xs[190] = 0.f; xs[191] = 0.f; }
  if (t < 128) { ssum[t] = 0.f; ssq[t] = 0.f; }
  if (t < 32) {
    p1[t * 104 + 0] = 0.f; p1[t * 104 + 1] = 0.f;
#pragma unroll
    for (int m = 95; m < 104; ++m) p1[t * 104 + m] = 0.f;
  }
  __syncthreads();
  // conv1 -> BN1 -> relu -> pool -> p1
  {
    int c = t & 31, g = t >> 5;
    float wr[5];
#pragma unroll
    for (int k = 0; k < 5; ++k) wr[k] = w1[c * 5 + k];
    float bias = b1[c], sc = sc1[c], sh = sh1[c];
    for (int lp = g; lp < 93; lp += 8) {
      int b0 = 2 * lp;
      float y0 = bias, y1 = bias;
#pragma unroll
      for (int k = 0; k < 5; ++k) {
        y0 = fmaf(xs[b0 + k], wr[k], y0);
        y1 = fmaf(xs[b0 + 1 + k], wr[k], y1);
      }
      y0 = fmaf(y0, sc, sh); y1 = fmaf(y1, sc, sh);
      p1[c * 104 + 2 + lp] = fmaxf(fmaxf(y0, y1), 0.f);
    }
  }
  __syncthreads();
  // conv2 into regs
  int oc = (t & 15) * 4, g2 = t >> 4, l0 = g2 * 6;
  float acc[4][6] = {};
  for (int i = 0; i < 32; ++i) {
    float xv[10];
#pragma unroll
    for (int j = 0; j < 10; ++j) xv[j] = p1[i * 104 + l0 + j];
#pragma unroll
    for (int k = 0; k < 5; ++k) {
      const float4 wv = *reinterpret_cast<const float4*>(&w2t[(i * 5 + k) * 64 + oc]);
#pragma unroll
      for (int j = 0; j < 6; ++j) {
        acc[0][j] = fmaf(xv[j + k], wv.x, acc[0][j]);
        acc[1][j] = fmaf(xv[j + k], wv.y, acc[1][j]);
        acc[2][j] = fmaf(xv[j + k], wv.z, acc[2][j]);
        acc[3][j] = fmaf(xv[j + k], wv.w, acc[3][j]);
      }
    }
  }
  __syncthreads();   // all reads of p1/w2t complete; region reused as p2/w3t below
  // BN2(final)+relu+pool -> p2
#pragma unroll
  for (int c = 0; c < 4; ++c) {
    int ch = oc + c;
    float bias = b2[ch], sc = sc2[ch], sh = sh2[ch];
#pragma unroll
    for (int u = 0; u < 3; ++u) {
      int pp = 3 * g2 + u;
      if (pp < 46) {
        float ya = fmaf(acc[c][2 * u] + bias, sc, sh);
        float yb = fmaf(acc[c][2 * u + 1] + bias, sc, sh);
        p2[ch * 52 + 2 + pp] = fmaxf(fmaxf(ya, yb), 0.f);
      }
    }
  }
  if (t < 64) {
    p2[t * 52 + 0] = 0.f; p2[t * 52 + 1] = 0.f;
    p2[t * 52 + 48] = 0.f; p2[t * 52 + 49] = 0.f; p2[t * 52 + 50] = 0.f; p2[t * 52 + 51] = 0.f;
  }
  // conv3 in 2 halves of output channels
  for (int h = 0; h < 2; ++h) {
    __syncthreads();
    for (int i = t; i < 20480; i += 256) w3t[(i % 320) * 64 + (i / 320)] = f2bf(w3[h * 20480 + i]);
    __syncthreads();
    int oc2 = (t & 31) * 2, gb = t >> 5, l0b = gb * 6;
    float a2[2][6] = {};
    for (int i = 0; i < 64; ++i) {
      float xv[10];
#pragma unroll
      for (int j = 0; j < 10; ++j) xv[j] = p2[i * 52 + l0b + j];
#pragma unroll
      for (int k = 0; k < 5; ++k) {
        unsigned wp = *reinterpret_cast<const unsigned*>(&w3t[(i * 5 + k) * 64 + oc2]);
        float wa = us2f((unsigned short)(wp & 0xffffu));
        float wb = us2f((unsigned short)(wp >> 16));
#pragma unroll
        for (int j = 0; j < 6; ++j) {
          a2[0][j] = fmaf(xv[j + k], wa, a2[0][j]);
          a2[1][j] = fmaf(xv[j + k], wb, a2[1][j]);
        }
      }
    }
#pragma unroll
    for (int c = 0; c < 2; ++c) {
      int ch = h * 64 + oc2 + c;
      float bias3 = b3[ch], s = 0.f, s2 = 0.f;
      float yv[6];
#pragma unroll
      for (int j = 0; j < 6; ++j) {
        yv[j] = a2[c][j] + bias3;
        if (l0b + j < 46) { s += yv[j]; s2 = fmaf(yv[j], yv[j], s2); }
      }
#pragma unroll
      for (int u = 0; u < 3; ++u) {
        int pp = 3 * gb + u;
        if (pp < 23) praw3[(size_t)n * 2944 + ch * 23 + pp] = f2bf(fmaxf(yv[2 * u], yv[2 * u + 1]));
      }
      atomicAdd(&ssum[ch], s); atomicAdd(&ssq[ch], s2);
    }
  }
  __syncthreads();
  if (t < 128) { atomicAdd(&statacc[t], ssum[t]); atomicAdd(&statacc[128 + t], ssq[t]); }
}

// ---------------- efc1 GEMM with fused BN3+relu on pooled-raw A ------------------------------------
__global__ __launch_bounds__(256) void k_efc1(const bf16* __restrict__ praw,
    const float* __restrict__ sc3, const float* __restrict__ sh3,
    const float* __restrict__ W, const float* __restrict__ bias, float* __restrict__ C)
{
  const int M = NS, K = 2944, O = 256;
  __shared__ float As[16][68];
  __shared__ float Bs[16][68];
  __shared__ float scs[128], shs[128];
  int tid = threadIdx.x;
  if (tid < 128) { scs[tid] = sc3[tid]; shs[tid] = sh3[tid]; }
  __syncthreads();
  int bm = blockIdx.x * 64, bo = blockIdx.y * 64;
  int lr = tid >> 2, lk = (tid & 3) * 4;
  int tm = (tid & 15) * 4, to = (tid >> 4) * 4;
  float acc[4][4] = {};
  for (int k0 = 0; k0 < K; k0 += 16) {
    float a0 = 0.f, a1 = 0.f, a2 = 0.f, a3 = 0.f;
    float4 wv = make_float4(0.f, 0.f, 0.f, 0.f);
    int arow = bm + lr;
    if (arow < M) {
      int kb = k0 + lk;
      ushort4 u4 = *reinterpret_cast<const ushort4*>(praw + (size_t)arow * K + kb);
      int c0 = (kb + 0) / 23, c1 = (kb + 1) / 23, c2 = (kb + 2) / 23, c3 = (kb + 3) / 23;
      a0 = fmaxf(fmaf(us2f(u4.x), scs[c0], shs[c0]), 0.f);
      a1 = fmaxf(fmaf(us2f(u4.y), scs[c1], shs[c1]), 0.f);
      a2 = fmaxf(fmaf(us2f(u4.z), scs[c2], shs[c2]), 0.f);
      a3 = fmaxf(fmaf(us2f(u4.w), scs[c3], shs[c3]), 0.f);
    }
    int orow = bo + lr;
    if (orow < O) wv = load4f(W + (size_t)orow * K + k0 + lk);
    As[lk + 0][lr] = a0; As[lk + 1][lr] = a1; As[lk + 2][lr] = a2; As[lk + 3][lr] = a3;
    Bs[lk + 0][lr] = wv.x; Bs[lk + 1][lr] = wv.y; Bs[lk + 2][lr] = wv.z; Bs[lk + 3][lr] = wv.w;
    __syncthreads();
#pragma unroll
    for (int k = 0; k < 16; ++k) {
      const float4 a = *reinterpret_cast<const float4*>(&As[k][tm]);
      const float4 b = *reinterpret_cast<const float4*>(&Bs[k][to]);
      float a4[4] = {a.x, a.y, a.z, a.w};
      float b4[4] = {b.x, b.y, b.z, b.w};
#pragma unroll
      for (int i = 0; i < 4; ++i)
#pragma unroll
        for (int j = 0; j < 4; ++j) acc[i][j] = fmaf(a4[i], b4[j], acc[i][j]);
    }
    __syncthreads();
  }
#pragma unroll
  for (int i = 0; i < 4; ++i) {
    int row = bm + tm + i;
    if (row >= M) continue;
#pragma unroll
    for (int j = 0; j < 4; ++j) {
      int col = bo + to + j;
      float v = acc[i][j] + bias[col];
      C[(size_t)row * O + col] = fmaxf(v, 0.f);
    }
  }
}

// ---------------- Generic tiled GEMM: C[m,o] = act( sum_k A[m,k]*W[o,k] (+bias[o]) (*rscale[m]) ) --
template <typename OT, bool RELU, bool RSCALE>
__global__ __launch_bounds__(256) void k_gemm(const float* __restrict__ A, const float* __restrict__ W,
    const float* __restrict__ bias, const float* __restrict__ rscale,
    OT* __restrict__ C, int M, int K, int O)
{
  __shared__ float As[16][68];
  __shared__ float Bs[16][68];
  int tid = threadIdx.x;
  int bm = blockIdx.x * 64, bo = blockIdx.y * 64;
  int lr = tid >> 2, lk = (tid & 3) * 4;
  int tm = (tid & 15) * 4, to = (tid >> 4) * 4;
  float acc[4][4] = {};
  for (int k0 = 0; k0 < K; k0 += 16) {
    float4 av = make_float4(0.f, 0.f, 0.f, 0.f);
    float4 wv = make_float4(0.f, 0.f, 0.f, 0.f);
    int arow = bm + lr;
    if (arow < M) av = load4f(A + (size_t)arow * K + k0 + lk);
    int orow = bo + lr;
    if (orow < O) wv = load4f(W + (size_t)orow * K + k0 + lk);
    As[lk + 0][lr] = av.x; As[lk + 1][lr] = av.y; As[lk + 2][lr] = av.z; As[lk + 3][lr] = av.w;
    Bs[lk + 0][lr] = wv.x; Bs[lk + 1][lr] = wv.y; Bs[lk + 2][lr] = wv.z; Bs[lk + 3][lr] = wv.w;
    __syncthreads();
#pragma unroll
    for (int k = 0; k < 16; ++k) {
      const float4 a = *reinterpret_cast<const float4*>(&As[k][tm]);
      const float4 b = *reinterpret_cast<const float4*>(&Bs[k][to]);
      float a4[4] = {a.x, a.y, a.z, a.w};
      float b4[4] = {b.x, b.y, b.z, b.w};
#pragma unroll
      for (int i = 0; i < 4; ++i)
#pragma unroll
        for (int j = 0; j < 4; ++j) acc[i][j] = fmaf(a4[i], b4[j], acc[i][j]);
    }
    __syncthreads();
  }
#pragma unroll
  for (int i = 0; i < 4; ++i) {
    int row = bm + tm + i;
    if (row >= M) continue;
    float rs = RSCALE ? rscale[row] : 1.f;
#pragma unroll
    for (int j = 0; j < 4; ++j) {
      int col = bo + to + j;
      if (col >= O) continue;
      float v = acc[i][j];
      if (bias) v += bias[col];
      if (RSCALE) v *= rs;
      if (RELU) v = fmaxf(v, 0.f);
      storeOut(&C[(size_t)row * O + col], v);
    }
  }
}

// ---------------- GCN helpers ----------------------------------------------------------------------
__global__ void k_fill1(float* __restrict__ p, int n)
{
  int i = blockIdx.x * 256 + threadIdx.x;
  if (i < n) p[i] = 1.f;
}
__global__ void k_degacc(const int* __restrict__ dst, float* __restrict__ deg)
{
  int e = blockIdx.x * 256 + threadIdx.x;
  if (e < NE) atomicAdd(&deg[dst[e]], 1.f);
}
__global__ void k_dinv(float* __restrict__ deg)
{
  int i = blockIdx.x * 256 + threadIdx.x;
  if (i < NS) deg[i] = rsqrtf(fmaxf(deg[i], 1e-12f));
}
__global__ __launch_bounds__(256) void k_scatter(const int* __restrict__ src, const int* __restrict__ dst,
    const float* __restrict__ hs, float* __restrict__ agg)
{
  int tid = blockIdx.x * 256 + threadIdx.x;
  if (tid >= NE * 32) return;
  int e = tid >> 5, q = tid & 31;
  int s = src[e], d = dst[e];
  float4 v = reinterpret_cast<const float4*>(hs)[(size_t)s * 32 + q];
  float* o = agg + (size_t)d * 128 + q * 4;
  atomicAdd(o + 0, v.x); atomicAdd(o + 1, v.y); atomicAdd(o + 2, v.z); atomicAdd(o + 3, v.w);
}
__global__ void k_gcn_post(const float* __restrict__ agg, const float* __restrict__ hs,
    const float* __restrict__ dinv, const float* __restrict__ b, float* __restrict__ out, int relu)
{
  int total = NS * 128;
  for (int i = blockIdx.x * 256 + threadIdx.x; i < total; i += gridDim.x * 256) {
    int n = i >> 7, f = i & 127;
    float v = (agg[i] + hs[i]) * dinv[n] + b[f];
    if (relu) v = fmaxf(v, 0.f);
    out[i] = v;
  }
}

// ---------------- decoder input concat: [z | cls_emb[label]] ---------------------------------------
__global__ void k_dcat(const float* __restrict__ z, const int* __restrict__ labels,
    const float* __restrict__ emb, float* __restrict__ dcat)
{
  int total = NS * 160;
  for (int i = blockIdx.x * 256 + threadIdx.x; i < total; i += gridDim.x * 256) {
    int n = i / 160, f = i % 160;
    dcat[i] = (f < 128) ? z[(size_t)n * 128 + f] : emb[labels[n] * 32 + (f - 128)];
  }
}

// ---------------- convT1: (N,128,23)->(N,64,46), stride2 pad1 K4, + stats --------------------------
__global__ __launch_bounds__(256) void k_convT1(const bf16* __restrict__ d2,
    const float* __restrict__ w, const float* __restrict__ b,
    bf16* __restrict__ raw, float* __restrict__ stats)
{
  __shared__ float xsh[2944];     // [128][23]
  __shared__ __align__(8) bf16 wsh[16384];     // half of (128,64,4) by input channel
  __shared__ float ssum[64], ssq[64];
  int n = blockIdx.x, t = threadIdx.x;
  for (int i = t; i < 2944; i += 256) xsh[i] = bf2f(d2[(size_t)n * 2944 + i]);
  if (t < 64) { ssum[t] = 0.f; ssq[t] = 0.f; }
  int o = t & 63, g = t >> 6;     // g 0..3 -> positions 12g..12g+11
  float acc[12] = {};
  for (int half = 0; half < 2; ++half) {
    __syncthreads();
    for (int i = t; i < 16384; i += 256) wsh[i] = f2bf(w[half * 16384 + i]);
    __syncthreads();
    for (int i = 0; i < 64; ++i) {
      int ci = half * 64 + i;
      ushort4 w4 = *reinterpret_cast<const ushort4*>(&wsh[i * 256 + o * 4]);
      float w0 = us2f(w4.x), w1 = us2f(w4.y), w2v = us2f(w4.z), w3v = us2f(w4.w);
      float xl[8];
#pragma unroll
      for (int m = 0; m < 8; ++m) {
        int l = 6 * g - 1 + m;
        xl[m] = (l >= 0 && l < 23) ? xsh[ci * 23 + l] : 0.f;
      }
#pragma unroll
      for (int j = 0; j < 12; ++j) {
        if (j & 1) acc[j] = fmaf(w0, xl[(j + 1) / 2 + 1], fmaf(w2v, xl[(j + 1) / 2], acc[j]));
        else       acc[j] = fmaf(w1, xl[j / 2 + 1],       fmaf(w3v, xl[j / 2],       acc[j]));
      }
    }
  }
  float bias = b[o], s = 0.f, s2 = 0.f;
  size_t base = (size_t)n * 2944;   // 64*46
#pragma unroll
  for (int j = 0; j < 12; ++j) {
    int tp = 12 * g + j;
    if (tp < 46) {
      float y = acc[j] + bias;
      raw[base + (size_t)o * 46 + tp] = f2bf(y);
      s += y; s2 = fmaf(y, y, s2);
    }
  }
  atomicAdd(&ssum[o], s); atomicAdd(&ssq[o], s2);
  __syncthreads();
  if (t < 64) { atomicAdd(&stats[t], ssum[t]); atomicAdd(&stats[128 + t], ssq[t]); }
}

// ---------------- convT2: (BN1d+relu on raw1) -> (N,32,92), + stats --------------------------------
__global__ __launch_bounds__(256) void k_convT2(const bf16* __restrict__ raw1,
    const float* __restrict__ sc, const float* __restrict__ sh,
    const float* __restrict__ w, const float* __restrict__ b,
    bf16* __restrict__ raw2out, float* __restrict__ stats)
{
  __shared__ float xsh[2944];     // [64][46]
  __shared__ __align__(16) float wsh[8192];     // (64,32,4)
  __shared__ float ssum[32], ssq[32];
  int n = blockIdx.x, t = threadIdx.x;
  for (int i = t; i < 8192; i += 256) wsh[i] = w[i];
  for (int i = t; i < 2944; i += 256) {
    int c = i / 46;
    float v = fmaf(bf2f(raw1[(size_t)n * 2944 + i]), sc[c], sh[c]);
    xsh[i] = fmaxf(v, 0.f);
  }
  if (t < 32) { ssum[t] = 0.f; ssq[t] = 0.f; }
  __syncthreads();
  int o = t & 31, g = t >> 5;     // 8 groups x 12 positions (92 valid)
  float acc[12] = {};
  for (int i = 0; i < 64; ++i) {
    const float4 wv = *reinterpret_cast<const float4*>(&wsh[i * 128 + o * 4]);
    float w0 = wv.x, w1 = wv.y, w2v = wv.z, w3v = wv.w;
    float xl[8];
#pragma unroll
    for (int m = 0; m < 8; ++m) {
      int l = 6 * g - 1 + m;
      xl[m] = (l >= 0 && l < 46) ? xsh[i * 46 + l] : 0.f;
    }
#pragma unroll
    for (int j = 0; j < 12; ++j) {
      if (j & 1) acc[j] = fmaf(w0, xl[(j + 1) / 2 + 1], fmaf(w2v, xl[(j + 1) / 2], acc[j]));
      else       acc[j] = fmaf(w1, xl[j / 2 + 1],       fmaf(w3v, xl[j / 2],       acc[j]));
    }
  }
  float bias = b[o], s = 0.f, s2 = 0.f;
  size_t base = (size_t)n * 2944;   // 32*92
#pragma unroll
  for (int j = 0; j < 12; ++j) {
    int tp = 12 * g + j;
    if (tp < 92) {
      float y = acc[j] + bias;
      raw2out[base + (size_t)o * 92 + tp] = f2bf(y);
      s += y; s2 = fmaf(y, y, s2);
    }
  }
  atomicAdd(&ssum[o], s); atomicAdd(&ssq[o], s2);
  __syncthreads();
  if (t < 32) { atomicAdd(&stats[t], ssum[t]); atomicAdd(&stats[128 + t], ssq[t]); }
}

// ---------------- convT3: (BN2d+relu on raw2) -> (N,1,184) -> recon padded to 187 ------------------
__global__ __launch_bounds__(256) void k_convT3(const bf16* __restrict__ raw2,
    const float* __restrict__ sc, const float* __restrict__ sh,
    const float* __restrict__ w, const float* __restrict__ b,
    float* __restrict__ recon)
{
  __shared__ float xsh[2944];   // [32][92]
  __shared__ float wsh[128];
  int n = blockIdx.x, t = threadIdx.x;
  if (t < 128) wsh[t] = w[t];
  for (int i = t; i < 2944; i += 256) {
    int c = i / 92;
    float v = fmaf(bf2f(raw2[(size_t)n * 2944 + i]), sc[c], sh[c]);
    xsh[i] = fmaxf(v, 0.f);
  }
  __syncthreads();
  if (t < 187) {
    float y = 0.f;
    if (t < 184) {
      y = b[0];
      if (t & 1) {
        int l1 = (t + 1) / 2, l2 = (t - 1) / 2;
        for (int i = 0; i < 32; ++i) {
          float a0 = (l1 < 92) ? wsh[i * 4 + 0] * xsh[i * 92 + l1] : 0.f;
          y += a0 + wsh[i * 4 + 2] * xsh[i * 92 + l2];
        }
      } else {
        int l1 = t / 2, l2 = t / 2 - 1;
        for (int i = 0; i < 32; ++i) {
          float a3 = (l2 >= 0) ? wsh[i * 4 + 3] * xsh[i * 92 + l2] : 0.f;
          y += wsh[i * 4 + 1] * xsh[i * 92 + l1] + a3;
        }
      }
    }
    recon[(size_t)n * 187 + t] = y;
  }
}

// ===================================================================================================
extern "C" void kernel_launch(void* const* d_in, const int* in_sizes, int n_in,
                              void* d_out, int out_size, void* d_ws, size_t ws_size,
                              hipStream_t stream)
{
  const float* wav    = (const float*)d_in[0];
  const int*   edges  = (const int*)d_in[1];     // [0..E)=src, [E..2E)=dst (int32)
  const int*   labels = (const int*)d_in[2];
  int a = 3;
  const float* ec1_w = (const float*)d_in[a++]; const float* ec1_b = (const float*)d_in[a++];
  const float* bn1e_g = (const float*)d_in[a++]; const float* bn1e_b = (const float*)d_in[a++];
  const float* ec2_w = (const float*)d_in[a++]; const float* ec2_b = (const float*)d_in[a++];
  const float* bn2e_g = (const float*)d_in[a++]; const float* bn2e_b = (const float*)d_in[a++];
  const float* ec3_w = (const float*)d_in[a++]; const float* ec3_b = (const float*)d_in[a++];
  const float* bn3e_g = (const float*)d_in[a++]; const float* bn3e_b = (const float*)d_in[a++];
  const float* efc1_w = (const float*)d_in[a++]; const float* efc1_b = (const float*)d_in[a++];
  const float* efc2_w = (const float*)d_in[a++]; const float* efc2_b = (const float*)d_in[a++];
  const float* g1_w = (const float*)d_in[a++]; const float* g1_b = (const float*)d_in[a++];
  const float* g2_w = (const float*)d_in[a++]; const float* g2_b = (const float*)d_in[a++];
  const float* c1_w = (const float*)d_in[a++]; const float* c1_b = (const float*)d_in[a++];
  const float* c2_w = (const float*)d_in[a++]; const float* c2_b = (const float*)d_in[a++];
  const float* cls_emb = (const float*)d_in[a++];
  const float* dfc1_w = (const float*)d_in[a++]; const float* dfc1_b = (const float*)d_in[a++];
  const float* dfc2_w = (const float*)d_in[a++]; const float* dfc2_b = (const float*)d_in[a++];
  const float* dc1_w = (const float*)d_in[a++]; const float* dc1_b = (const float*)d_in[a++];
  const float* bn1d_g = (const float*)d_in[a++]; const float* bn1d_b = (const float*)d_in[a++];
  const float* dc2_w = (const float*)d_in[a++]; const float* dc2_b = (const float*)d_in[a++];
  const float* bn2d_g = (const float*)d_in[a++]; const float* bn2d_b = (const float*)d_in[a++];
  const float* dc3_w = (const float*)d_in[a++]; const float* dc3_b = (const float*)d_in[a++];

  // workspace layout — total 235,524,096 bytes
  char* ws = (char*)d_ws;
  bf16*  B1 = (bf16*)(ws + 0);               // 58,880,000 bf16: praw3 -> d2 -> raw2out
  bf16*  B2 = (bf16*)(ws + 117760000ULL);    // 58,880,000 bf16: (GCN floats below) -> raw1
  float* E1 = (float*)(ws + 117760000ULL);   // (N,256)
  float* FE = (float*)(ws + 138240000ULL);   // (N,128)
  float* LN = (float*)(ws + 148480000ULL);   // (N,128)
  float* AG = (float*)(ws + 158720000ULL);   // (N,128)
  float* DI = (float*)(ws + 168960000ULL);   // (N)
  float* DC = (float*)(ws + 169040000ULL);   // (N,160) ends at 181,840,000
  float* ST = (float*)(ws + 235520000ULL);   // 1024 floats: sums + 3x scale/shift slots

  float* zout   = (float*)d_out;             // (N,128)
  float* recon  = (float*)d_out + 2560000;   // (N,187)
  float* logits = (float*)d_out + 6300000;   // (N,5)

  // ---- encoder ----
  (void)hipMemsetAsync(ST, 0, 1024, stream);
  k_conv1_stats<<<NS, 256, 0, stream>>>(wav, ec1_w, ec1_b, ST);
  k_bn_finalize<<<1, 128, 0, stream>>>(ST, bn1e_g, bn1e_b, 32, 1.f / (NS * 187.f), 256);
  (void)hipMemsetAsync(ST, 0, 1024, stream);
  k_s2stats<<<NS, 256, 0, stream>>>(wav, ec1_w, ec1_b, ST + 256, ST + 384, ec2_w, ec2_b, ST);
  k_bn_finalize<<<1, 128, 0, stream>>>(ST, bn2e_g, bn2e_b, 64, 1.f / (NS * 93.f), 512);
  (void)hipMemsetAsync(ST, 0, 1024, stream);
  k_s123<<<NS, 256, 0, stream>>>(wav, ec1_w, ec1_b, ST + 256, ST + 384, ec2_w, ec2_b,
                                 ST + 512, ST + 640, ec3_w, ec3_b, B1, ST);
  k_bn_finalize<<<1, 128, 0, stream>>>(ST, bn3e_g, bn3e_b, 128, 1.f / (NS * 46.f), 768);
  k_efc1<<<dim3(313, 4), 256, 0, stream>>>(B1, ST + 768, ST + 896, efc1_w, efc1_b, E1);
  k_gemm<float, false, false><<<dim3(313, 2), 256, 0, stream>>>(E1, efc2_w, efc2_b, nullptr, FE, NS, 256, 128);

  // ---- GCN ----
  k_fill1<<<79, 256, 0, stream>>>(DI, NS);
  k_degacc<<<2500, 256, 0, stream>>>(edges + NE, DI);
  k_dinv<<<79, 256, 0, stream>>>(DI);
  k_gemm<float, false, true><<<dim3(313, 2), 256, 0, stream>>>(FE, g1_w, nullptr, DI, LN, NS, 128, 128);
  (void)hipMemsetAsync(AG, 0, (size_t)NS * 128 * 4, stream);
  k_scatter<<<80000, 256, 0, stream>>>(edges, edges + NE, LN, AG);
  k_gcn_post<<<2560, 256, 0, stream>>>(AG, LN, DI, g1_b, FE, 1);   // h -> FE
  k_gemm<float, false, true><<<dim3(313, 2), 256, 0, stream>>>(FE, g2_w, nullptr, DI, LN, NS, 128, 128);
  (void)hipMemsetAsync(AG, 0, (size_t)NS * 128 * 4, stream);
  k_scatter<<<80000, 256, 0, stream>>>(edges, edges + NE, LN, AG);
  k_gcn_post<<<2560, 256, 0, stream>>>(AG, LN, DI, g2_b, zout, 0); // z -> d_out

  // ---- classifier ----
  k_gemm<float, true, false><<<dim3(313, 1), 256, 0, stream>>>(zout, c1_w, c1_b, nullptr, AG, NS, 128, 64);
  k_gemm<float, false, false><<<dim3(313, 1), 256, 0, stream>>>(AG, c2_w, c2_b, nullptr, logits, NS, 64, 5);

  // ---- decoder ----
  k_dcat<<<4096, 256, 0, stream>>>(zout, labels, cls_emb, DC);
  k_gemm<float, true, false><<<dim3(313, 4), 256, 0, stream>>>(DC, dfc1_w, dfc1_b, nullptr, E1, NS, 160, 256);
  k_gemm<bf16, true, false><<<dim3(313, 46), 256, 0, stream>>>(E1, dfc2_w, dfc2_b, nullptr, B1, NS, 256, 2944);
  (void)hipMemsetAsync(ST, 0, 1024, stream);
  k_convT1<<<NS, 256, 0, stream>>>(B1, dc1_w, dc1_b, B2, ST);
  k_bn_finalize<<<1, 128, 0, stream>>>(ST, bn1d_g, bn1d_b, 64, 1.f / (NS * 46.f), 256);
  (void)hipMemsetAsync(ST, 0, 1024, stream);
  k_convT2<<<NS, 256, 0, stream>>>(B2, ST + 256, ST + 384, dc2_w, dc2_b, B1, ST);
  k_bn_finalize<<<1, 128, 0, stream>>>(ST, bn2d_g, bn2d_b, 32, 1.f / (NS * 92.f), 512);
  k_convT3<<<NS, 256, 0, stream>>>(B1, ST + 512, ST + 640, dc3_w, dc3_b, recon);
}

// Round 5
// 5735.165 us; speedup vs baseline: 3.0800x; 1.6587x over previous
//
#include <hip/hip_runtime.h>
#include <hip/hip_bf16.h>

using bf16 = __hip_bfloat16;

#define NS 20000
#define NE 640000
#define BN_EPS 1e-5f

__device__ __forceinline__ float bf2f(bf16 x) { return __bfloat162float(x); }
__device__ __forceinline__ bf16 f2bf(float x) { return __float2bfloat16(x); }
__device__ __forceinline__ float us2f(unsigned short u) { return __uint_as_float(((unsigned)u) << 16); }

__device__ __forceinline__ float4 load4f(const float* p) { return *reinterpret_cast<const float4*>(p); }
__device__ __forceinline__ void storeOut(float* p, float v) { *p = v; }
__device__ __forceinline__ void storeOut(bf16* p, float v) { *p = f2bf(v); }

// ---------------- weight prep: transpose conv2/conv3 weights once into [tap][oc] globals -----------
__global__ __launch_bounds__(256) void k_wprep(const float* __restrict__ w2, const float* __restrict__ w3,
    float* __restrict__ W2T, bf16* __restrict__ W3T)
{
  int i = blockIdx.x * 256 + threadIdx.x;
  if (i < 10240) { int oc = i / 160, tap = i % 160; W2T[tap * 64 + oc] = w2[i]; }
  if (i < 40960) {
    int h = i / 20480, r = i % 20480;
    int oc = r / 320, tap = r % 320;
    W3T[h * 20480 + tap * 64 + oc] = f2bf(w3[i]);
  }
}

// ---------------- conv1 stats: accumulate per-channel sum/sumsq of raw conv1 ----------------------
__global__ __launch_bounds__(256) void k_conv1_stats(const float* __restrict__ wav,
    const float* __restrict__ w1, const float* __restrict__ b1, float* __restrict__ stats)
{
  __shared__ float xs[192];
  __shared__ float ssum[32], ssq[32];
  int n = blockIdx.x, t = threadIdx.x;
  if (t < 187) xs[2 + t] = wav[n * 187 + t];
  else if (t == 187) { xs[0] = 0.f; xs[1] = 0.f; }
  else if (t == 188) { xs[189] = 0.f; xs[190] = 0.f; xs[191] = 0.f; }
  if (t < 32) { ssum[t] = 0.f; ssq[t] = 0.f; }
  __syncthreads();
  int c = t & 31, g = t >> 5;
  float wr[5];
#pragma unroll
  for (int k = 0; k < 5; ++k) wr[k] = w1[c * 5 + k];
  float bias = b1[c], s = 0.f, s2 = 0.f;
  for (int l = g; l < 187; l += 8) {
    float y = bias;
#pragma unroll
    for (int k = 0; k < 5; ++k) y = fmaf(xs[l + k], wr[k], y);
    s += y; s2 = fmaf(y, y, s2);
  }
  atomicAdd(&ssum[c], s); atomicAdd(&ssq[c], s2);
  __syncthreads();
  if (t < 32) { atomicAdd(&stats[t], ssum[t]); atomicAdd(&stats[128 + t], ssq[t]); }
}

// ---------------- BN finalize: sum@[0..C), sumsq@[128..128+C) -> scale@off, shift@off+128 ----------
__global__ void k_bn_finalize(float* __restrict__ stats, const float* __restrict__ g,
                              const float* __restrict__ b, int C, float invCnt, int off)
{
  int t = threadIdx.x;
  if (t < C) {
    float mean = stats[t] * invCnt;
    float var = stats[128 + t] * invCnt - mean * mean;
    float sc = g[t] * rsqrtf(var + BN_EPS);
    stats[off + t] = sc;
    stats[off + 128 + t] = b[t] - mean * sc;
  }
}

// ---------------- pass A: conv1 -> BN1 -> relu -> pool -> conv2 -> stats2 only ---------------------
// W2T global is pre-transposed [tap(160)][oc(64)]; staged linearly (conflict-free).
__global__ __launch_bounds__(256) void k_s2stats(const float* __restrict__ wav,
    const float* __restrict__ w1, const float* __restrict__ b1,
    const float* __restrict__ sc1, const float* __restrict__ sh1,
    const float* __restrict__ W2T, const float* __restrict__ b2,
    float* __restrict__ statacc)
{
  __shared__ float xs[192];
  __shared__ float p1[32 * 104];   // cols 0..1 & 95..103 zero; data at 2+lp, lp<93
  __shared__ __align__(16) float w2t[10240];   // [160][64]
  __shared__ float ssum[64], ssq[64];
  int n = blockIdx.x, t = threadIdx.x;
  for (int i = t; i < 2560; i += 256)
    reinterpret_cast<float4*>(w2t)[i] = reinterpret_cast<const float4*>(W2T)[i];
  if (t < 187) xs[2 + t] = wav[n * 187 + t];
  else if (t == 187) { xs[0] = 0.f; xs[1] = 0.f; }
  else if (t == 188) { xs[189] = 0.f; xs[190] = 0.f; xs[191] = 0.f; }
  if (t < 64) { ssum[t] = 0.f; ssq[t] = 0.f; }
  if (t < 32) {
    p1[t * 104 + 0] = 0.f; p1[t * 104 + 1] = 0.f;
#pragma unroll
    for (int m = 95; m < 104; ++m) p1[t * 104 + m] = 0.f;
  }
  __syncthreads();
  {
    int c = t & 31, g = t >> 5;
    float wr[5];
#pragma unroll
    for (int k = 0; k < 5; ++k) wr[k] = w1[c * 5 + k];
    float bias = b1[c], sc = sc1[c], sh = sh1[c];
    for (int lp = g; lp < 93; lp += 8) {
      int b0 = 2 * lp;
      float y0 = bias, y1 = bias;
#pragma unroll
      for (int k = 0; k < 5; ++k) {
        y0 = fmaf(xs[b0 + k], wr[k], y0);
        y1 = fmaf(xs[b0 + 1 + k], wr[k], y1);
      }
      y0 = fmaf(y0, sc, sh); y1 = fmaf(y1, sc, sh);
      p1[c * 104 + 2 + lp] = fmaxf(fmaxf(y0, y1), 0.f);
    }
  }
  __syncthreads();
  int oc = (t & 15) * 4, l0 = (t >> 4) * 6;
  float acc[4][6] = {};
  for (int i = 0; i < 32; ++i) {
    float xv[10];
#pragma unroll
    for (int j = 0; j < 10; ++j) xv[j] = p1[i * 104 + l0 + j];
#pragma unroll
    for (int k = 0; k < 5; ++k) {
      const float4 wv = *reinterpret_cast<const float4*>(&w2t[(i * 5 + k) * 64 + oc]);
#pragma unroll
      for (int j = 0; j < 6; ++j) {
        acc[0][j] = fmaf(xv[j + k], wv.x, acc[0][j]);
        acc[1][j] = fmaf(xv[j + k], wv.y, acc[1][j]);
        acc[2][j] = fmaf(xv[j + k], wv.z, acc[2][j]);
        acc[3][j] = fmaf(xv[j + k], wv.w, acc[3][j]);
      }
    }
  }
#pragma unroll
  for (int c = 0; c < 4; ++c) {
    float bias = b2[oc + c], s = 0.f, s2 = 0.f;
#pragma unroll
    for (int j = 0; j < 6; ++j) {
      if (l0 + j < 93) {
        float y = acc[c][j] + bias;
        s += y; s2 = fmaf(y, y, s2);
      }
    }
    atomicAdd(&ssum[oc + c], s); atomicAdd(&ssq[oc + c], s2);
  }
  __syncthreads();
  if (t < 64) { atomicAdd(&statacc[t], ssum[t]); atomicAdd(&statacc[128 + t], ssq[t]); }
}

// ---------------- pass B: conv1->BN1->pool->conv2->BN2->pool->conv3 -> pooled-raw3 + stats3 --------
// Stores max(raw3[2p], raw3[2p+1]) (valid because BN3 gamma=1>0: pool commutes with BN+relu).
// W2T/W3T globals pre-transposed [tap][oc]; staged linearly (conflict-free writes AND reads).
__global__ __launch_bounds__(256) void k_s123(const float* __restrict__ wav,
    const float* __restrict__ w1, const float* __restrict__ b1,
    const float* __restrict__ sc1, const float* __restrict__ sh1,
    const float* __restrict__ W2T, const float* __restrict__ b2,
    const float* __restrict__ sc2, const float* __restrict__ sh2,
    const bf16* __restrict__ W3T, const float* __restrict__ b3,
    bf16* __restrict__ praw3, float* __restrict__ statacc)
{
  __shared__ float xs[192];
  __shared__ float ssum[128], ssq[128];
  __shared__ __align__(16) char Rb[54272];
  float* p1  = (float*)Rb;            // [32][104] (phases 1-2)
  float* w2t = (float*)(Rb + 13312);  // [160][64] (phases 0-2)
  float* p2  = (float*)Rb;            // [64][52]  (phase 3; overlays p1)
  bf16*  w3t = (bf16*)(Rb + 13312);   // [320][64] per half (phase 3; overlays w2t)
  int n = blockIdx.x, t = threadIdx.x;
  for (int i = t; i < 2560; i += 256)
    reinterpret_cast<float4*>(w2t)[i] = reinterpret_cast<const float4*>(W2T)[i];
  if (t < 187) xs[2 + t] = wav[n * 187 + t];
  else if (t == 187) { xs[0] = 0.f; xs[1] = 0.f; }
  else if (t == 188) { xs[189] = 0.f; xs[190] = 0.f; xs[191] = 0.f; }
  if (t < 128) { ssum[t] = 0.f; ssq[t] = 0.f; }
  if (t < 32) {
    p1[t * 104 + 0] = 0.f; p1[t * 104 + 1] = 0.f;
#pragma unroll
    for (int m = 95; m < 104; ++m) p1[t * 104 + m] = 0.f;
  }
  __syncthreads();
  // conv1 -> BN1 -> relu -> pool -> p1
  {
    int c = t & 31, g = t >> 5;
    float wr[5];
#pragma unroll
    for (int k = 0; k < 5; ++k) wr[k] = w1[c * 5 + k];
    float bias = b1[c], sc = sc1[c], sh = sh1[c];
    for (int lp = g; lp < 93; lp += 8) {
      int b0 = 2 * lp;
      float y0 = bias, y1 = bias;
#pragma unroll
      for (int k = 0; k < 5; ++k) {
        y0 = fmaf(xs[b0 + k], wr[k], y0);
        y1 = fmaf(xs[b0 + 1 + k], wr[k], y1);
      }
      y0 = fmaf(y0, sc, sh); y1 = fmaf(y1, sc, sh);
      p1[c * 104 + 2 + lp] = fmaxf(fmaxf(y0, y1), 0.f);
    }
  }
  __syncthreads();
  // conv2 into regs
  int oc = (t & 15) * 4, g2 = t >> 4, l0 = g2 * 6;
  float acc[4][6] = {};
  for (int i = 0; i < 32; ++i) {
    float xv[10];
#pragma unroll
    for (int j = 0; j < 10; ++j) xv[j] = p1[i * 104 + l0 + j];
#pragma unroll
    for (int k = 0; k < 5; ++k) {
      const float4 wv = *reinterpret_cast<const float4*>(&w2t[(i * 5 + k) * 64 + oc]);
#pragma unroll
      for (int j = 0; j < 6; ++j) {
        acc[0][j] = fmaf(xv[j + k], wv.x, acc[0][j]);
        acc[1][j] = fmaf(xv[j + k], wv.y, acc[1][j]);
        acc[2][j] = fmaf(xv[j + k], wv.z, acc[2][j]);
        acc[3][j] = fmaf(xv[j + k], wv.w, acc[3][j]);
      }
    }
  }
  __syncthreads();   // all reads of p1/w2t complete; region reused as p2/w3t below
  // BN2(final)+relu+pool -> p2
#pragma unroll
  for (int c = 0; c < 4; ++c) {
    int ch = oc + c;
    float bias = b2[ch], sc = sc2[ch], sh = sh2[ch];
#pragma unroll
    for (int u = 0; u < 3; ++u) {
      int pp = 3 * g2 + u;
      if (pp < 46) {
        float ya = fmaf(acc[c][2 * u] + bias, sc, sh);
        float yb = fmaf(acc[c][2 * u + 1] + bias, sc, sh);
        p2[ch * 52 + 2 + pp] = fmaxf(fmaxf(ya, yb), 0.f);
      }
    }
  }
  if (t < 64) {
    p2[t * 52 + 0] = 0.f; p2[t * 52 + 1] = 0.f;
    p2[t * 52 + 48] = 0.f; p2[t * 52 + 49] = 0.f; p2[t * 52 + 50] = 0.f; p2[t * 52 + 51] = 0.f;
  }
  // conv3 in 2 halves of output channels
  for (int h = 0; h < 2; ++h) {
    __syncthreads();
    for (int i = t; i < 10240; i += 256)
      reinterpret_cast<unsigned*>(w3t)[i] = reinterpret_cast<const unsigned*>(W3T + h * 20480)[i];
    __syncthreads();
    int oc2 = (t & 31) * 2, gb = t >> 5, l0b = gb * 6;
    float a2[2][6] = {};
    for (int i = 0; i < 64; ++i) {
      float xv[10];
#pragma unroll
      for (int j = 0; j < 10; ++j) xv[j] = p2[i * 52 + l0b + j];
#pragma unroll
      for (int k = 0; k < 5; ++k) {
        unsigned wp = *reinterpret_cast<const unsigned*>(&w3t[(i * 5 + k) * 64 + oc2]);
        float wa = us2f((unsigned short)(wp & 0xffffu));
        float wb = us2f((unsigned short)(wp >> 16));
#pragma unroll
        for (int j = 0; j < 6; ++j) {
          a2[0][j] = fmaf(xv[j + k], wa, a2[0][j]);
          a2[1][j] = fmaf(xv[j + k], wb, a2[1][j]);
        }
      }
    }
#pragma unroll
    for (int c = 0; c < 2; ++c) {
      int ch = h * 64 + oc2 + c;
      float bias3 = b3[ch], s = 0.f, s2 = 0.f;
      float yv[6];
#pragma unroll
      for (int j = 0; j < 6; ++j) {
        yv[j] = a2[c][j] + bias3;
        if (l0b + j < 46) { s += yv[j]; s2 = fmaf(yv[j], yv[j], s2); }
      }
#pragma unroll
      for (int u = 0; u < 3; ++u) {
        int pp = 3 * gb + u;
        if (pp < 23) praw3[(size_t)n * 2944 + ch * 23 + pp] = f2bf(fmaxf(yv[2 * u], yv[2 * u + 1]));
      }
      atomicAdd(&ssum[ch], s); atomicAdd(&ssq[ch], s2);
    }
  }
  __syncthreads();
  if (t < 128) { atomicAdd(&statacc[t], ssum[t]); atomicAdd(&statacc[128 + t], ssq[t]); }
}

// ---------------- efc1 GEMM with fused BN3+relu on pooled-raw A ------------------------------------
__global__ __launch_bounds__(256) void k_efc1(const bf16* __restrict__ praw,
    const float* __restrict__ sc3, const float* __restrict__ sh3,
    const float* __restrict__ W, const float* __restrict__ bias, float* __restrict__ C)
{
  const int M = NS, K = 2944, O = 256;
  __shared__ float As[16][68];
  __shared__ float Bs[16][68];
  __shared__ float scs[128], shs[128];
  int tid = threadIdx.x;
  if (tid < 128) { scs[tid] = sc3[tid]; shs[tid] = sh3[tid]; }
  __syncthreads();
  int bm = blockIdx.x * 64, bo = blockIdx.y * 64;
  int lr = tid >> 2, lk = (tid & 3) * 4;
  int tm = (tid & 15) * 4, to = (tid >> 4) * 4;
  float acc[4][4] = {};
  for (int k0 = 0; k0 < K; k0 += 16) {
    float a0 = 0.f, a1 = 0.f, a2 = 0.f, a3 = 0.f;
    float4 wv = make_float4(0.f, 0.f, 0.f, 0.f);
    int arow = bm + lr;
    if (arow < M) {
      int kb = k0 + lk;
      ushort4 u4 = *reinterpret_cast<const ushort4*>(praw + (size_t)arow * K + kb);
      int c0 = (kb + 0) / 23, c1 = (kb + 1) / 23, c2 = (kb + 2) / 23, c3 = (kb + 3) / 23;
      a0 = fmaxf(fmaf(us2f(u4.x), scs[c0], shs[c0]), 0.f);
      a1 = fmaxf(fmaf(us2f(u4.y), scs[c1], shs[c1]), 0.f);
      a2 = fmaxf(fmaf(us2f(u4.z), scs[c2], shs[c2]), 0.f);
      a3 = fmaxf(fmaf(us2f(u4.w), scs[c3], shs[c3]), 0.f);
    }
    int orow = bo + lr;
    if (orow < O) wv = load4f(W + (size_t)orow * K + k0 + lk);
    As[lk + 0][lr] = a0; As[lk + 1][lr] = a1; As[lk + 2][lr] = a2; As[lk + 3][lr] = a3;
    Bs[lk + 0][lr] = wv.x; Bs[lk + 1][lr] = wv.y; Bs[lk + 2][lr] = wv.z; Bs[lk + 3][lr] = wv.w;
    __syncthreads();
#pragma unroll
    for (int k = 0; k < 16; ++k) {
      const float4 a = *reinterpret_cast<const float4*>(&As[k][tm]);
      const float4 b = *reinterpret_cast<const float4*>(&Bs[k][to]);
      float a4[4] = {a.x, a.y, a.z, a.w};
      float b4[4] = {b.x, b.y, b.z, b.w};
#pragma unroll
      for (int i = 0; i < 4; ++i)
#pragma unroll
        for (int j = 0; j < 4; ++j) acc[i][j] = fmaf(a4[i], b4[j], acc[i][j]);
    }
    __syncthreads();
  }
#pragma unroll
  for (int i = 0; i < 4; ++i) {
    int row = bm + tm + i;
    if (row >= M) continue;
#pragma unroll
    for (int j = 0; j < 4; ++j) {
      int col = bo + to + j;
      float v = acc[i][j] + bias[col];
      C[(size_t)row * O + col] = fmaxf(v, 0.f);
    }
  }
}

// ---------------- Generic tiled GEMM: C[m,o] = act( sum_k A[m,k]*W[o,k] (+bias[o]) (*rscale[m]) ) --
template <typename OT, bool RELU, bool RSCALE>
__global__ __launch_bounds__(256) void k_gemm(const float* __restrict__ A, const float* __restrict__ W,
    const float* __restrict__ bias, const float* __restrict__ rscale,
    OT* __restrict__ C, int M, int K, int O)
{
  __shared__ float As[16][68];
  __shared__ float Bs[16][68];
  int tid = threadIdx.x;
  int bm = blockIdx.x * 64, bo = blockIdx.y * 64;
  int lr = tid >> 2, lk = (tid & 3) * 4;
  int tm = (tid & 15) * 4, to = (tid >> 4) * 4;
  float acc[4][4] = {};
  for (int k0 = 0; k0 < K; k0 += 16) {
    float4 av = make_float4(0.f, 0.f, 0.f, 0.f);
    float4 wv = make_float4(0.f, 0.f, 0.f, 0.f);
    int arow = bm + lr;
    if (arow < M) av = load4f(A + (size_t)arow * K + k0 + lk);
    int orow = bo + lr;
    if (orow < O) wv = load4f(W + (size_t)orow * K + k0 + lk);
    As[lk + 0][lr] = av.x; As[lk + 1][lr] = av.y; As[lk + 2][lr] = av.z; As[lk + 3][lr] = av.w;
    Bs[lk + 0][lr] = wv.x; Bs[lk + 1][lr] = wv.y; Bs[lk + 2][lr] = wv.z; Bs[lk + 3][lr] = wv.w;
    __syncthreads();
#pragma unroll
    for (int k = 0; k < 16; ++k) {
      const float4 a = *reinterpret_cast<const float4*>(&As[k][tm]);
      const float4 b = *reinterpret_cast<const float4*>(&Bs[k][to]);
      float a4[4] = {a.x, a.y, a.z, a.w};
      float b4[4] = {b.x, b.y, b.z, b.w};
#pragma unroll
      for (int i = 0; i < 4; ++i)
#pragma unroll
        for (int j = 0; j < 4; ++j) acc[i][j] = fmaf(a4[i], b4[j], acc[i][j]);
    }
    __syncthreads();
  }
#pragma unroll
  for (int i = 0; i < 4; ++i) {
    int row = bm + tm + i;
    if (row >= M) continue;
    float rs = RSCALE ? rscale[row] : 1.f;
#pragma unroll
    for (int j = 0; j < 4; ++j) {
      int col = bo + to + j;
      if (col >= O) continue;
      float v = acc[i][j];
      if (bias) v += bias[col];
      if (RSCALE) v *= rs;
      if (RELU) v = fmaxf(v, 0.f);
      storeOut(&C[(size_t)row * O + col], v);
    }
  }
}

// ---------------- GCN: degree count (int), scan, dinv, CSR place, aggregate ------------------------
__global__ void k_degacc_int(const int* __restrict__ dst, int* __restrict__ dg)
{
  int e = blockIdx.x * 256 + threadIdx.x;
  if (e < NE) atomicAdd(&dg[dst[e]], 1);
}
__global__ __launch_bounds__(1024) void k_scan(const int* __restrict__ dg,
    int* __restrict__ off, int* __restrict__ cur)
{
  __shared__ int part[1024];
  int t = threadIdx.x;
  int base = t * 20;
  int local[20];
  int s = 0;
#pragma unroll
  for (int k = 0; k < 20; ++k) {
    int idx = base + k;
    int v = (idx < NS) ? dg[idx] : 0;
    local[k] = s; s += v;
  }
  part[t] = s;
  __syncthreads();
  for (int d = 1; d < 1024; d <<= 1) {
    int v = (t >= d) ? part[t - d] : 0;
    __syncthreads();
    part[t] += v;
    __syncthreads();
  }
  int pre = (t > 0) ? part[t - 1] : 0;
#pragma unroll
  for (int k = 0; k < 20; ++k) {
    int idx = base + k;
    if (idx < NS) { off[idx] = pre + local[k]; cur[idx] = pre + local[k]; }
  }
  if (t == 1023) off[NS] = part[1023];
}
__global__ void k_dinv(const int* __restrict__ dg, float* __restrict__ dinv)
{
  int i = blockIdx.x * 256 + threadIdx.x;
  if (i < NS) dinv[i] = rsqrtf((float)(dg[i] + 1));
}
__global__ void k_place(const int* __restrict__ src, const int* __restrict__ dst,
    int* __restrict__ cur, int* __restrict__ csr_src)
{
  int e = blockIdx.x * 256 + threadIdx.x;
  if (e < NE) {
    int p = atomicAdd(&cur[dst[e]], 1);
    csr_src[p] = src[e];
  }
}
// out[n,f] = relu?( (sum_{in-edges} hs[src,f] + hs[n,f]) * dinv[n] + b[f] )
template <bool RELU>
__global__ __launch_bounds__(128) void k_gcn_agg(const int* __restrict__ off,
    const int* __restrict__ csr_src, const float* __restrict__ hs,
    const float* __restrict__ dinv, const float* __restrict__ b, float* __restrict__ out)
{
  __shared__ int sidx[128];
  int n = blockIdx.x, t = threadIdx.x;
  int s0 = off[n], s1 = off[n + 1];
  float acc = 0.f;
  for (int base = s0; base < s1; base += 128) {
    int cnt = min(128, s1 - base);
    if (t < cnt) sidx[t] = csr_src[base + t];
    __syncthreads();
    for (int i = 0; i < cnt; ++i) acc += hs[(size_t)sidx[i] * 128 + t];
    __syncthreads();
  }
  float v = (acc + hs[(size_t)n * 128 + t]) * dinv[n] + b[t];
  if (RELU) v = fmaxf(v, 0.f);
  out[(size_t)n * 128 + t] = v;
}

// ---------------- decoder input concat: [z | cls_emb[label]] ---------------------------------------
__global__ void k_dcat(const float* __restrict__ z, const int* __restrict__ labels,
    const float* __restrict__ emb, float* __restrict__ dcat)
{
  int total = NS * 160;
  for (int i = blockIdx.x * 256 + threadIdx.x; i < total; i += gridDim.x * 256) {
    int n = i / 160, f = i % 160;
    dcat[i] = (f < 128) ? z[(size_t)n * 128 + f] : emb[labels[n] * 32 + (f - 128)];
  }
}

// ---------------- convT1: (N,128,23)->(N,64,46), stride2 pad1 K4, + stats --------------------------
__global__ __launch_bounds__(256) void k_convT1(const bf16* __restrict__ d2,
    const float* __restrict__ w, const float* __restrict__ b,
    bf16* __restrict__ raw, float* __restrict__ stats)
{
  __shared__ float xsh[2944];     // [128][23]
  __shared__ __align__(8) bf16 wsh[16384];     // half of (128,64,4) by input channel
  __shared__ float ssum[64], ssq[64];
  int n = blockIdx.x, t = threadIdx.x;
  for (int i = t; i < 2944; i += 256) xsh[i] = bf2f(d2[(size_t)n * 2944 + i]);
  if (t < 64) { ssum[t] = 0.f; ssq[t] = 0.f; }
  int o = t & 63, g = t >> 6;     // g 0..3 -> positions 12g..12g+11
  float acc[12] = {};
  for (int half = 0; half < 2; ++half) {
    __syncthreads();
    for (int i = t; i < 16384; i += 256) wsh[i] = f2bf(w[half * 16384 + i]);
    __syncthreads();
    for (int i = 0; i < 64; ++i) {
      int ci = half * 64 + i;
      ushort4 w4 = *reinterpret_cast<const ushort4*>(&wsh[i * 256 + o * 4]);
      float w0 = us2f(w4.x), w1 = us2f(w4.y), w2v = us2f(w4.z), w3v = us2f(w4.w);
      float xl[8];
#pragma unroll
      for (int m = 0; m < 8; ++m) {
        int l = 6 * g - 1 + m;
        xl[m] = (l >= 0 && l < 23) ? xsh[ci * 23 + l] : 0.f;
      }
#pragma unroll
      for (int j = 0; j < 12; ++j) {
        if (j & 1) acc[j] = fmaf(w0, xl[(j + 1) / 2 + 1], fmaf(w2v, xl[(j + 1) / 2], acc[j]));
        else       acc[j] = fmaf(w1, xl[j / 2 + 1],       fmaf(w3v, xl[j / 2],       acc[j]));
      }
    }
  }
  float bias = b[o], s = 0.f, s2 = 0.f;
  size_t base = (size_t)n * 2944;   // 64*46
#pragma unroll
  for (int j = 0; j < 12; ++j) {
    int tp = 12 * g + j;
    if (tp < 46) {
      float y = acc[j] + bias;
      raw[base + (size_t)o * 46 + tp] = f2bf(y);
      s += y; s2 = fmaf(y, y, s2);
    }
  }
  atomicAdd(&ssum[o], s); atomicAdd(&ssq[o], s2);
  __syncthreads();
  if (t < 64) { atomicAdd(&stats[t], ssum[t]); atomicAdd(&stats[128 + t], ssq[t]); }
}

// ---------------- convT2: (BN1d+relu on raw1) -> (N,32,92), + stats --------------------------------
__global__ __launch_bounds__(256) void k_convT2(const bf16* __restrict__ raw1,
    const float* __restrict__ sc, const float* __restrict__ sh,
    const float* __restrict__ w, const float* __restrict__ b,
    bf16* __restrict__ raw2out, float* __restrict__ stats)
{
  __shared__ float xsh[2944];     // [64][46]
  __shared__ __align__(16) float wsh[8192];     // (64,32,4)
  __shared__ float ssum[32], ssq[32];
  int n = blockIdx.x, t = threadIdx.x;
  for (int i = t; i < 8192; i += 256) wsh[i] = w[i];
  for (int i = t; i < 2944; i += 256) {
    int c = i / 46;
    float v = fmaf(bf2f(raw1[(size_t)n * 2944 + i]), sc[c], sh[c]);
    xsh[i] = fmaxf(v, 0.f);
  }
  if (t < 32) { ssum[t] = 0.f; ssq[t] = 0.f; }
  __syncthreads();
  int o = t & 31, g = t >> 5;     // 8 groups x 12 positions (92 valid)
  float acc[12] = {};
  for (int i = 0; i < 64; ++i) {
    const float4 wv = *reinterpret_cast<const float4*>(&wsh[i * 128 + o * 4]);
    float w0 = wv.x, w1 = wv.y, w2v = wv.z, w3v = wv.w;
    float xl[8];
#pragma unroll
    for (int m = 0; m < 8; ++m) {
      int l = 6 * g - 1 + m;
      xl[m] = (l >= 0 && l < 46) ? xsh[i * 46 + l] : 0.f;
    }
#pragma unroll
    for (int j = 0; j < 12; ++j) {
      if (j & 1) acc[j] = fmaf(w0, xl[(j + 1) / 2 + 1], fmaf(w2v, xl[(j + 1) / 2], acc[j]));
      else       acc[j] = fmaf(w1, xl[j / 2 + 1],       fmaf(w3v, xl[j / 2],       acc[j]));
    }
  }
  float bias = b[o], s = 0.f, s2 = 0.f;
  size_t base = (size_t)n * 2944;   // 32*92
#pragma unroll
  for (int j = 0; j < 12; ++j) {
    int tp = 12 * g + j;
    if (tp < 92) {
      float y = acc[j] + bias;
      raw2out[base + (size_t)o * 92 + tp] = f2bf(y);
      s += y; s2 = fmaf(y, y, s2);
    }
  }
  atomicAdd(&ssum[o], s); atomicAdd(&ssq[o], s2);
  __syncthreads();
  if (t < 32) { atomicAdd(&stats[t], ssum[t]); atomicAdd(&stats[128 + t], ssq[t]); }
}

// ---------------- convT3: (BN2d+relu on raw2) -> (N,1,184) -> recon padded to 187 ------------------
__global__ __launch_bounds__(256) void k_convT3(const bf16* __restrict__ raw2,
    const float* __restrict__ sc, const float* __restrict__ sh,
    const float* __restrict__ w, const float* __restrict__ b,
    float* __restrict__ recon)
{
  __shared__ float xsh[2944];   // [32][92]
  __shared__ float wsh[128];
  int n = blockIdx.x, t = threadIdx.x;
  if (t < 128) wsh[t] = w[t];
  for (int i = t; i < 2944; i += 256) {
    int c = i / 92;
    float v = fmaf(bf2f(raw2[(size_t)n * 2944 + i]), sc[c], sh[c]);
    xsh[i] = fmaxf(v, 0.f);
  }
  __syncthreads();
  if (t < 187) {
    float y = 0.f;
    if (t < 184) {
      y = b[0];
      if (t & 1) {
        int l1 = (t + 1) / 2, l2 = (t - 1) / 2;
        for (int i = 0; i < 32; ++i) {
          float a0 = (l1 < 92) ? wsh[i * 4 + 0] * xsh[i * 92 + l1] : 0.f;
          y += a0 + wsh[i * 4 + 2] * xsh[i * 92 + l2];
        }
      } else {
        int l1 = t / 2, l2 = t / 2 - 1;
        for (int i = 0; i < 32; ++i) {
          float a3 = (l2 >= 0) ? wsh[i * 4 + 3] * xsh[i * 92 + l2] : 0.f;
          y += wsh[i * 4 + 1] * xsh[i * 92 + l1] + a3;
        }
      }
    }
    recon[(size_t)n * 187 + t] = y;
  }
}

// ===================================================================================================
extern "C" void kernel_launch(void* const* d_in, const int* in_sizes, int n_in,
                              void* d_out, int out_size, void* d_ws, size_t ws_size,
                              hipStream_t stream)
{
  const float* wav    = (const float*)d_in[0];
  const int*   edges  = (const int*)d_in[1];     // [0..E)=src, [E..2E)=dst (int32)
  const int*   labels = (const int*)d_in[2];
  int a = 3;
  const float* ec1_w = (const float*)d_in[a++]; const float* ec1_b = (const float*)d_in[a++];
  const float* bn1e_g = (const float*)d_in[a++]; const float* bn1e_b = (const float*)d_in[a++];
  const float* ec2_w = (const float*)d_in[a++]; const float* ec2_b = (const float*)d_in[a++];
  const float* bn2e_g = (const float*)d_in[a++]; const float* bn2e_b = (const float*)d_in[a++];
  const float* ec3_w = (const float*)d_in[a++]; const float* ec3_b = (const float*)d_in[a++];
  const float* bn3e_g = (const float*)d_in[a++]; const float* bn3e_b = (const float*)d_in[a++];
  const float* efc1_w = (const float*)d_in[a++]; const float* efc1_b = (const float*)d_in[a++];
  const float* efc2_w = (const float*)d_in[a++]; const float* efc2_b = (const float*)d_in[a++];
  const float* g1_w = (const float*)d_in[a++]; const float* g1_b = (const float*)d_in[a++];
  const float* g2_w = (const float*)d_in[a++]; const float* g2_b = (const float*)d_in[a++];
  const float* c1_w = (const float*)d_in[a++]; const float* c1_b = (const float*)d_in[a++];
  const float* c2_w = (const float*)d_in[a++]; const float* c2_b = (const float*)d_in[a++];
  const float* cls_emb = (const float*)d_in[a++];
  const float* dfc1_w = (const float*)d_in[a++]; const float* dfc1_b = (const float*)d_in[a++];
  const float* dfc2_w = (const float*)d_in[a++]; const float* dfc2_b = (const float*)d_in[a++];
  const float* dc1_w = (const float*)d_in[a++]; const float* dc1_b = (const float*)d_in[a++];
  const float* bn1d_g = (const float*)d_in[a++]; const float* bn1d_b = (const float*)d_in[a++];
  const float* dc2_w = (const float*)d_in[a++]; const float* dc2_b = (const float*)d_in[a++];
  const float* bn2d_g = (const float*)d_in[a++]; const float* bn2d_b = (const float*)d_in[a++];
  const float* dc3_w = (const float*)d_in[a++]; const float* dc3_b = (const float*)d_in[a++];

  // workspace layout — within 235,524,096 bytes
  char* ws = (char*)d_ws;
  bf16*  B1 = (bf16*)(ws + 0);               // 58,880,000 bf16: praw3 -> d2 -> raw2out
  bf16*  B2 = (bf16*)(ws + 117760000ULL);    // 58,880,000 bf16: (GCN floats below) -> raw1
  float* E1 = (float*)(ws + 117760000ULL);   // (N,256)
  float* FE = (float*)(ws + 138240000ULL);   // (N,128)
  float* LN = (float*)(ws + 148480000ULL);   // (N,128)
  float* AG = (float*)(ws + 158720000ULL);   // (N,128) classifier temp
  float* DI = (float*)(ws + 168960000ULL);   // (N) dinv
  float* DC = (float*)(ws + 169040000ULL);   // (N,160) ends at 181,840,000
  float* W2T = (float*)(ws + 182000000ULL);  // [160][64] f32
  bf16*  W3T = (bf16*)(ws + 182100000ULL);   // [2][320][64] bf16
  int*   DG  = (int*)(ws + 182200000ULL);    // (N) in-degree
  int*   OFF = (int*)(ws + 182300000ULL);    // (N+1) csr offsets
  int*   CUR = (int*)(ws + 182400000ULL);    // (N) cursors
  int*   SRC = (int*)(ws + 182500000ULL);    // (E) csr src-indices, ends 185,060,000
  float* ST = (float*)(ws + 235520000ULL);   // 1024 floats: sums + 3x scale/shift slots

  float* zout   = (float*)d_out;             // (N,128)
  float* recon  = (float*)d_out + 2560000;   // (N,187)
  float* logits = (float*)d_out + 6300000;   // (N,5)

  // ---- weight prep + GCN CSR build (independent of encoder) ----
  k_wprep<<<160, 256, 0, stream>>>(ec2_w, ec3_w, W2T, W3T);
  (void)hipMemsetAsync(DG, 0, NS * 4, stream);
  k_degacc_int<<<2500, 256, 0, stream>>>(edges + NE, DG);
  k_scan<<<1, 1024, 0, stream>>>(DG, OFF, CUR);
  k_dinv<<<79, 256, 0, stream>>>(DG, DI);
  k_place<<<2500, 256, 0, stream>>>(edges, edges + NE, CUR, SRC);

  // ---- encoder ----
  (void)hipMemsetAsync(ST, 0, 1024, stream);
  k_conv1_stats<<<NS, 256, 0, stream>>>(wav, ec1_w, ec1_b, ST);
  k_bn_finalize<<<1, 128, 0, stream>>>(ST, bn1e_g, bn1e_b, 32, 1.f / (NS * 187.f), 256);
  (void)hipMemsetAsync(ST, 0, 1024, stream);
  k_s2stats<<<NS, 256, 0, stream>>>(wav, ec1_w, ec1_b, ST + 256, ST + 384, W2T, ec2_b, ST);
  k_bn_finalize<<<1, 128, 0, stream>>>(ST, bn2e_g, bn2e_b, 64, 1.f / (NS * 93.f), 512);
  (void)hipMemsetAsync(ST, 0, 1024, stream);
  k_s123<<<NS, 256, 0, stream>>>(wav, ec1_w, ec1_b, ST + 256, ST + 384, W2T, ec2_b,
                                 ST + 512, ST + 640, W3T, ec3_b, B1, ST);
  k_bn_finalize<<<1, 128, 0, stream>>>(ST, bn3e_g, bn3e_b, 128, 1.f / (NS * 46.f), 768);
  k_efc1<<<dim3(313, 4), 256, 0, stream>>>(B1, ST + 768, ST + 896, efc1_w, efc1_b, E1);
  k_gemm<float, false, false><<<dim3(313, 2), 256, 0, stream>>>(E1, efc2_w, efc2_b, nullptr, FE, NS, 256, 128);

  // ---- GCN ----
  k_gemm<float, false, true><<<dim3(313, 2), 256, 0, stream>>>(FE, g1_w, nullptr, DI, LN, NS, 128, 128);
  k_gcn_agg<true><<<NS, 128, 0, stream>>>(OFF, SRC, LN, DI, g1_b, FE);
  k_gemm<float, false, true><<<dim3(313, 2), 256, 0, stream>>>(FE, g2_w, nullptr, DI, LN, NS, 128, 128);
  k_gcn_agg<false><<<NS, 128, 0, stream>>>(OFF, SRC, LN, DI, g2_b, zout);

  // ---- classifier ----
  k_gemm<float, true, false><<<dim3(313, 1), 256, 0, stream>>>(zout, c1_w, c1_b, nullptr, AG, NS, 128, 64);
  k_gemm<float, false, false><<<dim3(313, 1), 256, 0, stream>>>(AG, c2_w, c2_b, nullptr, logits, NS, 64, 5);

  // ---- decoder ----
  k_dcat<<<4096, 256, 0, stream>>>(zout, labels, cls_emb, DC);
  k_gemm<float, true, false><<<dim3(313, 4), 256, 0, stream>>>(DC, dfc1_w, dfc1_b, nullptr, E1, NS, 160, 256);
  k_gemm<bf16, true, false><<<dim3(313, 46), 256, 0, stream>>>(E1, dfc2_w, dfc2_b, nullptr, B1, NS, 256, 2944);
  (void)hipMemsetAsync(ST, 0, 1024, stream);
  k_convT1<<<NS, 256, 0, stream>>>(B1, dc1_w, dc1_b, B2, ST);
  k_bn_finalize<<<1, 128, 0, stream>>>(ST, bn1d_g, bn1d_b, 64, 1.f / (NS * 46.f), 256);
  (void)hipMemsetAsync(ST, 0, 1024, stream);
  k_convT2<<<NS, 256, 0, stream>>>(B2, ST + 256, ST + 384, dc2_w, dc2_b, B1, ST);
  k_bn_finalize<<<1, 128, 0, stream>>>(ST, bn2d_g, bn2d_b, 32, 1.f / (NS * 92.f), 512);
  k_convT3<<<NS, 256, 0, stream>>>(B1, ST + 512, ST + 640, dc3_w, dc3_b, recon);
}

// Round 10
// 4683.806 us; speedup vs baseline: 3.7714x; 1.2245x over previous
//
#include <hip/hip_runtime.h>
#include <hip/hip_bf16.h>

using bf16 = __hip_bfloat16;
typedef __attribute__((ext_vector_type(8))) short short8v;
typedef __attribute__((ext_vector_type(4))) float f32x4;

#define NS 20000
#define NE 640000
#define BN_EPS 1e-5f

__device__ __forceinline__ float bf2f(bf16 x) { return __bfloat162float(x); }
__device__ __forceinline__ bf16 f2bf(float x) { return __float2bfloat16(x); }
__device__ __forceinline__ float us2f(unsigned short u) { return __uint_as_float(((unsigned)u) << 16); }
__device__ __forceinline__ unsigned short bf_bits(float x) {
  bf16 b = f2bf(x);
  return *reinterpret_cast<unsigned short*>(&b);
}

__device__ __forceinline__ float4 load4f(const float* p) { return *reinterpret_cast<const float4*>(p); }
__device__ __forceinline__ void storeOut(float* p, float v) { *p = v; }
__device__ __forceinline__ void storeOut(bf16* p, float v) { *p = f2bf(v); }

// ---------------- weight prep: transpose conv2/conv3 weights once into [tap][oc] globals -----------
// W2T/W3T live in d_out's recon region (not written until k_convT3, after last use in k_s3).
__global__ __launch_bounds__(256) void k_wprep(const float* __restrict__ w2, const float* __restrict__ w3,
    float* __restrict__ W2T, bf16* __restrict__ W3T)
{
  int i = blockIdx.x * 256 + threadIdx.x;
  if (i < 10240) { int oc = i / 160, tap = i % 160; W2T[tap * 64 + oc] = w2[i]; }
  if (i < 40960) {
    int h = i / 20480, r = i % 20480;
    int oc = r / 320, tap = r % 320;
    W3T[h * 20480 + tap * 64 + oc] = f2bf(w3[i]);
  }
}

// ---------------- conv1 stats ----------------------------------------------------------------------
__global__ __launch_bounds__(256) void k_conv1_stats(const float* __restrict__ wav,
    const float* __restrict__ w1, const float* __restrict__ b1, float* __restrict__ stats)
{
  __shared__ float xs[192];
  __shared__ float ssum[32], ssq[32];
  int n = blockIdx.x, t = threadIdx.x;
  if (t < 187) xs[2 + t] = wav[n * 187 + t];
  else if (t == 187) { xs[0] = 0.f; xs[1] = 0.f; }
  else if (t == 188) { xs[189] = 0.f; xs[190] = 0.f; xs[191] = 0.f; }
  if (t < 32) { ssum[t] = 0.f; ssq[t] = 0.f; }
  __syncthreads();
  int c = t & 31, g = t >> 5;
  float wr[5];
#pragma unroll
  for (int k = 0; k < 5; ++k) wr[k] = w1[c * 5 + k];
  float bias = b1[c], s = 0.f, s2 = 0.f;
  for (int l = g; l < 187; l += 8) {
    float y = bias;
#pragma unroll
    for (int k = 0; k < 5; ++k) y = fmaf(xs[l + k], wr[k], y);
    s += y; s2 = fmaf(y, y, s2);
  }
  atomicAdd(&ssum[c], s); atomicAdd(&ssq[c], s2);
  __syncthreads();
  if (t < 32) { atomicAdd(&stats[t], ssum[t]); atomicAdd(&stats[128 + t], ssq[t]); }
}

// ---------------- BN finalize ----------------------------------------------------------------------
__global__ void k_bn_finalize(float* __restrict__ stats, const float* __restrict__ g,
                              const float* __restrict__ b, int C, float invCnt, int off)
{
  int t = threadIdx.x;
  if (t < C) {
    float mean = stats[t] * invCnt;
    float var = stats[128 + t] * invCnt - mean * mean;
    float sc = g[t] * rsqrtf(var + BN_EPS);
    stats[off + t] = sc;
    stats[off + 128 + t] = b[t] - mean * sc;
  }
}

// ---------------- pass A: conv1->BN1->relu->pool->conv2 -> stats2 + pooled raw2 store -------------
__global__ __launch_bounds__(256) void k_s12(const float* __restrict__ wav,
    const float* __restrict__ w1, const float* __restrict__ b1,
    const float* __restrict__ sc1, const float* __restrict__ sh1,
    const float* __restrict__ W2T, const float* __restrict__ b2,
    bf16* __restrict__ praw2, float* __restrict__ statacc)
{
  __shared__ float xs[192];
  __shared__ float p1[32 * 104];
  __shared__ __align__(16) float w2t[10240];   // [160][64]
  __shared__ float ssum[64], ssq[64];
  int n = blockIdx.x, t = threadIdx.x;
  for (int i = t; i < 2560; i += 256)
    reinterpret_cast<float4*>(w2t)[i] = reinterpret_cast<const float4*>(W2T)[i];
  if (t < 187) xs[2 + t] = wav[n * 187 + t];
  else if (t == 187) { xs[0] = 0.f; xs[1] = 0.f; }
  else if (t == 188) { xs[189] = 0.f; xs[190] = 0.f; xs[191] = 0.f; }
  if (t < 64) { ssum[t] = 0.f; ssq[t] = 0.f; }
  if (t < 32) {
    p1[t * 104 + 0] = 0.f; p1[t * 104 + 1] = 0.f;
#pragma unroll
    for (int m = 95; m < 104; ++m) p1[t * 104 + m] = 0.f;
  }
  __syncthreads();
  {
    int c = t & 31, g = t >> 5;
    float wr[5];
#pragma unroll
    for (int k = 0; k < 5; ++k) wr[k] = w1[c * 5 + k];
    float bias = b1[c], sc = sc1[c], sh = sh1[c];
    for (int lp = g; lp < 93; lp += 8) {
      int b0 = 2 * lp;
      float y0 = bias, y1 = bias;
#pragma unroll
      for (int k = 0; k < 5; ++k) {
        y0 = fmaf(xs[b0 + k], wr[k], y0);
        y1 = fmaf(xs[b0 + 1 + k], wr[k], y1);
      }
      y0 = fmaf(y0, sc, sh); y1 = fmaf(y1, sc, sh);
      p1[c * 104 + 2 + lp] = fmaxf(fmaxf(y0, y1), 0.f);
    }
  }
  __syncthreads();
  int oc = (t & 15) * 4, g2 = t >> 4, l0 = g2 * 6;
  float acc[4][6] = {};
  for (int i = 0; i < 32; ++i) {
    float xv[10];
#pragma unroll
    for (int j = 0; j < 10; ++j) xv[j] = p1[i * 104 + l0 + j];
#pragma unroll
    for (int k = 0; k < 5; ++k) {
      const float4 wv = *reinterpret_cast<const float4*>(&w2t[(i * 5 + k) * 64 + oc]);
#pragma unroll
      for (int j = 0; j < 6; ++j) {
        acc[0][j] = fmaf(xv[j + k], wv.x, acc[0][j]);
        acc[1][j] = fmaf(xv[j + k], wv.y, acc[1][j]);
        acc[2][j] = fmaf(xv[j + k], wv.z, acc[2][j]);
        acc[3][j] = fmaf(xv[j + k], wv.w, acc[3][j]);
      }
    }
  }
#pragma unroll
  for (int c = 0; c < 4; ++c) {
    int ch = oc + c;
    float bias = b2[ch], s = 0.f, s2 = 0.f;
#pragma unroll
    for (int j = 0; j < 6; ++j) {
      if (l0 + j < 93) {
        float y = acc[c][j] + bias;
        s += y; s2 = fmaf(y, y, s2);
      }
    }
    // pooled raw store (pre-BN; pool commutes with BN2+relu since gamma2 > 0)
#pragma unroll
    for (int u = 0; u < 3; ++u) {
      int pp = 3 * g2 + u;
      if (pp < 46)
        praw2[(size_t)n * 2944 + ch * 46 + pp] =
            f2bf(fmaxf(acc[c][2 * u] + bias, acc[c][2 * u + 1] + bias));
    }
    atomicAdd(&ssum[ch], s); atomicAdd(&ssq[ch], s2);
  }
  __syncthreads();
  if (t < 64) { atomicAdd(&statacc[t], ssum[t]); atomicAdd(&statacc[128 + t], ssq[t]); }
}

// ---------------- pass B: (praw2 -> BN2+relu) -> conv3 -> pooled-raw3 + stats3 ---------------------
__global__ __launch_bounds__(256) void k_s3(const bf16* __restrict__ praw2,
    const float* __restrict__ sc2, const float* __restrict__ sh2,
    const bf16* __restrict__ W3T, const float* __restrict__ b3,
    bf16* __restrict__ praw3, float* __restrict__ statacc)
{
  __shared__ float ssum[128], ssq[128];
  __shared__ __align__(16) char Rb[54272];   // p2 13312 B + w3t 20480 bf16 = 40960 B  (R8 bug: was 33792)
  float* p2  = (float*)Rb;            // [64][52]
  bf16*  w3t = (bf16*)(Rb + 13312);   // [320][64] per half
  int n = blockIdx.x, t = threadIdx.x;
  if (t < 128) { ssum[t] = 0.f; ssq[t] = 0.f; }
  if (t < 64) {
    p2[t * 52 + 0] = 0.f; p2[t * 52 + 1] = 0.f;
    p2[t * 52 + 48] = 0.f; p2[t * 52 + 49] = 0.f; p2[t * 52 + 50] = 0.f; p2[t * 52 + 51] = 0.f;
  }
  for (int i = t; i < 2944; i += 256) {
    int c = i / 46, lp = i % 46;
    float v = fmaf(bf2f(praw2[(size_t)n * 2944 + i]), sc2[c], sh2[c]);
    p2[c * 52 + 2 + lp] = fmaxf(v, 0.f);
  }
  for (int h = 0; h < 2; ++h) {
    __syncthreads();
    for (int i = t; i < 10240; i += 256)
      reinterpret_cast<unsigned*>(w3t)[i] = reinterpret_cast<const unsigned*>(W3T + h * 20480)[i];
    __syncthreads();
    int oc2 = (t & 31) * 2, gb = t >> 5, l0b = gb * 6;
    float a2[2][6] = {};
    for (int i = 0; i < 64; ++i) {
      float xv[10];
#pragma unroll
      for (int j = 0; j < 10; ++j) xv[j] = p2[i * 52 + l0b + j];
#pragma unroll
      for (int k = 0; k < 5; ++k) {
        unsigned wp = *reinterpret_cast<const unsigned*>(&w3t[(i * 5 + k) * 64 + oc2]);
        float wa = us2f((unsigned short)(wp & 0xffffu));
        float wb = us2f((unsigned short)(wp >> 16));
#pragma unroll
        for (int j = 0; j < 6; ++j) {
          a2[0][j] = fmaf(xv[j + k], wa, a2[0][j]);
          a2[1][j] = fmaf(xv[j + k], wb, a2[1][j]);
        }
      }
    }
#pragma unroll
    for (int c = 0; c < 2; ++c) {
      int ch = h * 64 + oc2 + c;
      float bias3 = b3[ch], s = 0.f, s2 = 0.f;
      float yv[6];
#pragma unroll
      for (int j = 0; j < 6; ++j) {
        yv[j] = a2[c][j] + bias3;
        if (l0b + j < 46) { s += yv[j]; s2 = fmaf(yv[j], yv[j], s2); }
      }
#pragma unroll
      for (int u = 0; u < 3; ++u) {
        int pp = 3 * gb + u;
        if (pp < 23) praw3[(size_t)n * 2944 + ch * 23 + pp] = f2bf(fmaxf(yv[2 * u], yv[2 * u + 1]));
      }
      atomicAdd(&ssum[ch], s); atomicAdd(&ssq[ch], s2);
    }
  }
  __syncthreads();
  if (t < 128) { atomicAdd(&statacc[t], ssum[t]); atomicAdd(&statacc[128 + t], ssq[t]); }
}

// ---------------- in-place BN3+relu on pooled raw3 (bf16), channel = (i%2944)/23 -------------------
__global__ __launch_bounds__(256) void k_bnrelu(bf16* __restrict__ x,
    const float* __restrict__ sc, const float* __restrict__ sh)
{
  int total = NS * 736;   // ushort4 granules; 2944 % 4 == 0 so granules never straddle rows
  for (int q = blockIdx.x * 256 + threadIdx.x; q < total; q += gridDim.x * 256) {
    ushort4 u = reinterpret_cast<ushort4*>(x)[q];
    int f = (q * 4) % 2944;
    int c0 = f / 23, c1 = (f + 1) / 23, c2 = (f + 2) / 23, c3 = (f + 3) / 23;
    ushort4 o;
    o.x = bf_bits(fmaxf(fmaf(us2f(u.x), sc[c0], sh[c0]), 0.f));
    o.y = bf_bits(fmaxf(fmaf(us2f(u.y), sc[c1], sh[c1]), 0.f));
    o.z = bf_bits(fmaxf(fmaf(us2f(u.z), sc[c2], sh[c2]), 0.f));
    o.w = bf_bits(fmaxf(fmaf(us2f(u.w), sc[c3], sh[c3]), 0.f));
    reinterpret_cast<ushort4*>(x)[q] = o;
  }
}

// ---------------- MFMA GEMM: C[m,o] = act(sum_k A[m,k]*W[o,k] + bias[o]); 128x128 tile -------------
// grid: x = O/128 (x fastest -> consecutive blocks share A-tile in L2), y = ceil(M/128). K%32==0.
template <typename AT, typename OT, bool RELU>
__global__ __launch_bounds__(256) void k_mgemm(const AT* __restrict__ A, const float* __restrict__ W,
    const float* __restrict__ bias, OT* __restrict__ C, int M, int K, int O)
{
  __shared__ __align__(16) bf16 As[128][40];
  __shared__ __align__(16) bf16 Bs[128][40];
  int t = threadIdx.x;
  int bm = blockIdx.y * 128, bo = blockIdx.x * 128;
  int wave = t >> 6, lane = t & 63;
  int wm = (wave & 1) * 64, wn = (wave >> 1) * 64;
  int srow = t >> 1, skc = (t & 1) * 16;
  f32x4 acc[4][4] = {};
  for (int k0 = 0; k0 < K; k0 += 32) {
    {
      short8v v0 = {}, v1 = {};
      int grow = bm + srow;
      if (grow < M) {
        if constexpr (sizeof(AT) == 2) {
          const short8v* src = reinterpret_cast<const short8v*>(A + (size_t)grow * K + k0 + skc);
          v0 = src[0]; v1 = src[1];
        } else {
          const float* src = (const float*)A + (size_t)grow * K + k0 + skc;
#pragma unroll
          for (int i = 0; i < 8; ++i) v0[i] = (short)bf_bits(src[i]);
#pragma unroll
          for (int i = 0; i < 8; ++i) v1[i] = (short)bf_bits(src[8 + i]);
        }
      }
      short8v* dst = reinterpret_cast<short8v*>(&As[srow][skc]);
      dst[0] = v0; dst[1] = v1;
    }
    {
      const float* src = W + (size_t)(bo + srow) * K + k0 + skc;
      short8v v0, v1;
#pragma unroll
      for (int i = 0; i < 8; ++i) v0[i] = (short)bf_bits(src[i]);
#pragma unroll
      for (int i = 0; i < 8; ++i) v1[i] = (short)bf_bits(src[8 + i]);
      short8v* dst = reinterpret_cast<short8v*>(&Bs[srow][skc]);
      dst[0] = v0; dst[1] = v1;
    }
    __syncthreads();
    short8v af[4], bf_[4];
#pragma unroll
    for (int i = 0; i < 4; ++i)
      af[i] = *reinterpret_cast<const short8v*>(&As[wm + 16 * i + (lane & 15)][(lane >> 4) * 8]);
#pragma unroll
    for (int j = 0; j < 4; ++j)
      bf_[j] = *reinterpret_cast<const short8v*>(&Bs[wn + 16 * j + (lane & 15)][(lane >> 4) * 8]);
#pragma unroll
    for (int i = 0; i < 4; ++i)
#pragma unroll
      for (int j = 0; j < 4; ++j)
        acc[i][j] = __builtin_amdgcn_mfma_f32_16x16x32_bf16(af[i], bf_[j], acc[i][j], 0, 0, 0);
    __syncthreads();
  }
#pragma unroll
  for (int i = 0; i < 4; ++i) {
#pragma unroll
    for (int j = 0; j < 4; ++j) {
      int col = bo + wn + 16 * j + (lane & 15);
      int row0 = bm + wm + 16 * i + (lane >> 4) * 4;
      float bv = bias[col];
#pragma unroll
      for (int r = 0; r < 4; ++r) {
        int row = row0 + r;
        if (row < M) {
          float v = acc[i][j][r] + bv;
          if (RELU) v = fmaxf(v, 0.f);
          storeOut(&C[(size_t)row * O + col], v);
        }
      }
    }
  }
}

// ---------------- Generic small tiled GEMM (fp32) --------------------------------------------------
template <typename OT, bool RELU, bool RSCALE>
__global__ __launch_bounds__(256) void k_gemm(const float* __restrict__ A, const float* __restrict__ W,
    const float* __restrict__ bias, const float* __restrict__ rscale,
    OT* __restrict__ C, int M, int K, int O)
{
  __shared__ float As[16][68];
  __shared__ float Bs[16][68];
  int tid = threadIdx.x;
  int bm = blockIdx.x * 64, bo = blockIdx.y * 64;
  int lr = tid >> 2, lk = (tid & 3) * 4;
  int tm = (tid & 15) * 4, to = (tid >> 4) * 4;
  float acc[4][4] = {};
  for (int k0 = 0; k0 < K; k0 += 16) {
    float4 av = make_float4(0.f, 0.f, 0.f, 0.f);
    float4 wv = make_float4(0.f, 0.f, 0.f, 0.f);
    int arow = bm + lr;
    if (arow < M) av = load4f(A + (size_t)arow * K + k0 + lk);
    int orow = bo + lr;
    if (orow < O) wv = load4f(W + (size_t)orow * K + k0 + lk);
    As[lk + 0][lr] = av.x; As[lk + 1][lr] = av.y; As[lk + 2][lr] = av.z; As[lk + 3][lr] = av.w;
    Bs[lk + 0][lr] = wv.x; Bs[lk + 1][lr] = wv.y; Bs[lk + 2][lr] = wv.z; Bs[lk + 3][lr] = wv.w;
    __syncthreads();
#pragma unroll
    for (int k = 0; k < 16; ++k) {
      const float4 a = *reinterpret_cast<const float4*>(&As[k][tm]);
      const float4 b = *reinterpret_cast<const float4*>(&Bs[k][to]);
      float a4[4] = {a.x, a.y, a.z, a.w};
      float b4[4] = {b.x, b.y, b.z, b.w};
#pragma unroll
      for (int i = 0; i < 4; ++i)
#pragma unroll
        for (int j = 0; j < 4; ++j) acc[i][j] = fmaf(a4[i], b4[j], acc[i][j]);
    }
    __syncthreads();
  }
#pragma unroll
  for (int i = 0; i < 4; ++i) {
    int row = bm + tm + i;
    if (row >= M) continue;
    float rs = RSCALE ? rscale[row] : 1.f;
#pragma unroll
    for (int j = 0; j < 4; ++j) {
      int col = bo + to + j;
      if (col >= O) continue;
      float v = acc[i][j];
      if (bias) v += bias[col];
      if (RSCALE) v *= rs;
      if (RELU) v = fmaxf(v, 0.f);
      storeOut(&C[(size_t)row * O + col], v);
    }
  }
}

// ---------------- GCN: degree count (int), scan, dinv, CSR place, aggregate ------------------------
__global__ void k_degacc_int(const int* __restrict__ dst, int* __restrict__ dg)
{
  int e = blockIdx.x * 256 + threadIdx.x;
  if (e < NE) atomicAdd(&dg[dst[e]], 1);
}
__global__ __launch_bounds__(1024) void k_scan(const int* __restrict__ dg,
    int* __restrict__ off, int* __restrict__ cur)
{
  __shared__ int part[1024];
  int t = threadIdx.x;
  int base = t * 20;
  int local[20];
  int s = 0;
#pragma unroll
  for (int k = 0; k < 20; ++k) {
    int idx = base + k;
    int v = (idx < NS) ? dg[idx] : 0;
    local[k] = s; s += v;
  }
  part[t] = s;
  __syncthreads();
  for (int d = 1; d < 1024; d <<= 1) {
    int v = (t >= d) ? part[t - d] : 0;
    __syncthreads();
    part[t] += v;
    __syncthreads();
  }
  int pre = (t > 0) ? part[t - 1] : 0;
#pragma unroll
  for (int k = 0; k < 20; ++k) {
    int idx = base + k;
    if (idx < NS) { off[idx] = pre + local[k]; cur[idx] = pre + local[k]; }
  }
  if (t == 1023) off[NS] = part[1023];
}
__global__ void k_dinv(const int* __restrict__ dg, float* __restrict__ dinv)
{
  int i = blockIdx.x * 256 + threadIdx.x;
  if (i < NS) dinv[i] = rsqrtf((float)(dg[i] + 1));
}
__global__ void k_place(const int* __restrict__ src, const int* __restrict__ dst,
    int* __restrict__ cur, int* __restrict__ csr_src)
{
  int e = blockIdx.x * 256 + threadIdx.x;
  if (e < NE) {
    int p = atomicAdd(&cur[dst[e]], 1);
    csr_src[p] = src[e];
  }
}
template <bool RELU>
__global__ __launch_bounds__(128) void k_gcn_agg(const int* __restrict__ off,
    const int* __restrict__ csr_src, const float* __restrict__ hs,
    const float* __restrict__ dinv, const float* __restrict__ b, float* __restrict__ out)
{
  __shared__ int sidx[128];
  int n = blockIdx.x, t = threadIdx.x;
  int s0 = off[n], s1 = off[n + 1];
  float acc = 0.f;
  for (int base = s0; base < s1; base += 128) {
    int cnt = min(128, s1 - base);
    if (t < cnt) sidx[t] = csr_src[base + t];
    __syncthreads();
    for (int i = 0; i < cnt; ++i) acc += hs[(size_t)sidx[i] * 128 + t];
    __syncthreads();
  }
  float v = (acc + hs[(size_t)n * 128 + t]) * dinv[n] + b[t];
  if (RELU) v = fmaxf(v, 0.f);
  out[(size_t)n * 128 + t] = v;
}

// ---------------- decoder input concat -------------------------------------------------------------
__global__ void k_dcat(const float* __restrict__ z, const int* __restrict__ labels,
    const float* __restrict__ emb, float* __restrict__ dcat)
{
  int total = NS * 160;
  for (int i = blockIdx.x * 256 + threadIdx.x; i < total; i += gridDim.x * 256) {
    int n = i / 160, f = i % 160;
    dcat[i] = (f < 128) ? z[(size_t)n * 128 + f] : emb[labels[n] * 32 + (f - 128)];
  }
}

// ---------------- convT1 ---------------------------------------------------------------------------
__global__ __launch_bounds__(256) void k_convT1(const bf16* __restrict__ d2,
    const float* __restrict__ w, const float* __restrict__ b,
    bf16* __restrict__ raw, float* __restrict__ stats)
{
  __shared__ float xsh[2944];
  __shared__ __align__(8) bf16 wsh[16384];
  __shared__ float ssum[64], ssq[64];
  int n = blockIdx.x, t = threadIdx.x;
  for (int i = t; i < 2944; i += 256) xsh[i] = bf2f(d2[(size_t)n * 2944 + i]);
  if (t < 64) { ssum[t] = 0.f; ssq[t] = 0.f; }
  int o = t & 63, g = t >> 6;
  float acc[12] = {};
  for (int half = 0; half < 2; ++half) {
    __syncthreads();
    for (int i = t; i < 16384; i += 256) wsh[i] = f2bf(w[half * 16384 + i]);
    __syncthreads();
    for (int i = 0; i < 64; ++i) {
      int ci = half * 64 + i;
      ushort4 w4 = *reinterpret_cast<const ushort4*>(&wsh[i * 256 + o * 4]);
      float w0 = us2f(w4.x), w1 = us2f(w4.y), w2v = us2f(w4.z), w3v = us2f(w4.w);
      float xl[8];
#pragma unroll
      for (int m = 0; m < 8; ++m) {
        int l = 6 * g - 1 + m;
        xl[m] = (l >= 0 && l < 23) ? xsh[ci * 23 + l] : 0.f;
      }
#pragma unroll
      for (int j = 0; j < 12; ++j) {
        if (j & 1) acc[j] = fmaf(w0, xl[(j + 1) / 2 + 1], fmaf(w2v, xl[(j + 1) / 2], acc[j]));
        else       acc[j] = fmaf(w1, xl[j / 2 + 1],       fmaf(w3v, xl[j / 2],       acc[j]));
      }
    }
  }
  float bias = b[o], s = 0.f, s2 = 0.f;
  size_t base = (size_t)n * 2944;
#pragma unroll
  for (int j = 0; j < 12; ++j) {
    int tp = 12 * g + j;
    if (tp < 46) {
      float y = acc[j] + bias;
      raw[base + (size_t)o * 46 + tp] = f2bf(y);
      s += y; s2 = fmaf(y, y, s2);
    }
  }
  atomicAdd(&ssum[o], s); atomicAdd(&ssq[o], s2);
  __syncthreads();
  if (t < 64) { atomicAdd(&stats[t], ssum[t]); atomicAdd(&stats[128 + t], ssq[t]); }
}

// ---------------- convT2 ---------------------------------------------------------------------------
__global__ __launch_bounds__(256) void k_convT2(const bf16* __restrict__ raw1,
    const float* __restrict__ sc, const float* __restrict__ sh,
    const float* __restrict__ w, const float* __restrict__ b,
    bf16* __restrict__ raw2out, float* __restrict__ stats)
{
  __shared__ float xsh[2944];
  __shared__ __align__(16) float wsh[8192];
  __shared__ float ssum[32], ssq[32];
  int n = blockIdx.x, t = threadIdx.x;
  for (int i = t; i < 8192; i += 256) wsh[i] = w[i];
  for (int i = t; i < 2944; i += 256) {
    int c = i / 46;
    float v = fmaf(bf2f(raw1[(size_t)n * 2944 + i]), sc[c], sh[c]);
    xsh[i] = fmaxf(v, 0.f);
  }
  if (t < 32) { ssum[t] = 0.f; ssq[t] = 0.f; }
  __syncthreads();
  int o = t & 31, g = t >> 5;
  float acc[12] = {};
  for (int i = 0; i < 64; ++i) {
    const float4 wv = *reinterpret_cast<const float4*>(&wsh[i * 128 + o * 4]);
    float w0 = wv.x, w1 = wv.y, w2v = wv.z, w3v = wv.w;
    float xl[8];
#pragma unroll
    for (int m = 0; m < 8; ++m) {
      int l = 6 * g - 1 + m;
      xl[m] = (l >= 0 && l < 46) ? xsh[i * 46 + l] : 0.f;
    }
#pragma unroll
    for (int j = 0; j < 12; ++j) {
      if (j & 1) acc[j] = fmaf(w0, xl[(j + 1) / 2 + 1], fmaf(w2v, xl[(j + 1) / 2], acc[j]));
      else       acc[j] = fmaf(w1, xl[j / 2 + 1],       fmaf(w3v, xl[j / 2],       acc[j]));
    }
  }
  float bias = b[o], s = 0.f, s2 = 0.f;
  size_t base = (size_t)n * 2944;
#pragma unroll
  for (int j = 0; j < 12; ++j) {
    int tp = 12 * g + j;
    if (tp < 92) {
      float y = acc[j] + bias;
      raw2out[base + (size_t)o * 92 + tp] = f2bf(y);
      s += y; s2 = fmaf(y, y, s2);
    }
  }
  atomicAdd(&ssum[o], s); atomicAdd(&ssq[o], s2);
  __syncthreads();
  if (t < 32) { atomicAdd(&stats[t], ssum[t]); atomicAdd(&stats[128 + t], ssq[t]); }
}

// ---------------- convT3 ---------------------------------------------------------------------------
__global__ __launch_bounds__(256) void k_convT3(const bf16* __restrict__ raw2,
    const float* __restrict__ sc, const float* __restrict__ sh,
    const float* __restrict__ w, const float* __restrict__ b,
    float* __restrict__ recon)
{
  __shared__ float xsh[2944];
  __shared__ float wsh[128];
  int n = blockIdx.x, t = threadIdx.x;
  if (t < 128) wsh[t] = w[t];
  for (int i = t; i < 2944; i += 256) {
    int c = i / 92;
    float v = fmaf(bf2f(raw2[(size_t)n * 2944 + i]), sc[c], sh[c]);
    xsh[i] = fmaxf(v, 0.f);
  }
  __syncthreads();
  if (t < 187) {
    float y = 0.f;
    if (t < 184) {
      y = b[0];
      if (t & 1) {
        int l1 = (t + 1) / 2, l2 = (t - 1) / 2;
        for (int i = 0; i < 32; ++i) {
          float a0 = (l1 < 92) ? wsh[i * 4 + 0] * xsh[i * 92 + l1] : 0.f;
          y += a0 + wsh[i * 4 + 2] * xsh[i * 92 + l2];
        }
      } else {
        int l1 = t / 2, l2 = t / 2 - 1;
        for (int i = 0; i < 32; ++i) {
          float a3 = (l2 >= 0) ? wsh[i * 4 + 3] * xsh[i * 92 + l2] : 0.f;
          y += wsh[i * 4 + 1] * xsh[i * 92 + l1] + a3;
        }
      }
    }
    recon[(size_t)n * 187 + t] = y;
  }
}

// ===================================================================================================
extern "C" void kernel_launch(void* const* d_in, const int* in_sizes, int n_in,
                              void* d_out, int out_size, void* d_ws, size_t ws_size,
                              hipStream_t stream)
{
  const float* wav    = (const float*)d_in[0];
  const int*   edges  = (const int*)d_in[1];
  const int*   labels = (const int*)d_in[2];
  int a = 3;
  const float* ec1_w = (const float*)d_in[a++]; const float* ec1_b = (const float*)d_in[a++];
  const float* bn1e_g = (const float*)d_in[a++]; const float* bn1e_b = (const float*)d_in[a++];
  const float* ec2_w = (const float*)d_in[a++]; const float* ec2_b = (const float*)d_in[a++];
  const float* bn2e_g = (const float*)d_in[a++]; const float* bn2e_b = (const float*)d_in[a++];
  const float* ec3_w = (const float*)d_in[a++]; const float* ec3_b = (const float*)d_in[a++];
  const float* bn3e_g = (const float*)d_in[a++]; const float* bn3e_b = (const float*)d_in[a++];
  const float* efc1_w = (const float*)d_in[a++]; const float* efc1_b = (const float*)d_in[a++];
  const float* efc2_w = (const float*)d_in[a++]; const float* efc2_b = (const float*)d_in[a++];
  const float* g1_w = (const float*)d_in[a++]; const float* g1_b = (const float*)d_in[a++];
  const float* g2_w = (const float*)d_in[a++]; const float* g2_b = (const float*)d_in[a++];
  const float* c1_w = (const float*)d_in[a++]; const float* c1_b = (const float*)d_in[a++];
  const float* c2_w = (const float*)d_in[a++]; const float* c2_b = (const float*)d_in[a++];
  const float* cls_emb = (const float*)d_in[a++];
  const float* dfc1_w = (const float*)d_in[a++]; const float* dfc1_b = (const float*)d_in[a++];
  const float* dfc2_w = (const float*)d_in[a++]; const float* dfc2_b = (const float*)d_in[a++];
  const float* dc1_w = (const float*)d_in[a++]; const float* dc1_b = (const float*)d_in[a++];
  const float* bn1d_g = (const float*)d_in[a++]; const float* bn1d_b = (const float*)d_in[a++];
  const float* dc2_w = (const float*)d_in[a++]; const float* dc2_b = (const float*)d_in[a++];
  const float* bn2d_g = (const float*)d_in[a++]; const float* bn2d_b = (const float*)d_in[a++];
  const float* dc3_w = (const float*)d_in[a++]; const float* dc3_b = (const float*)d_in[a++];

  // workspace layout — within the proven-safe 235,524,096 bytes
  char* ws = (char*)d_ws;
  bf16*  B1 = (bf16*)(ws + 0);               // praw3 -> d2 -> raw2out          (117.76 MB)
  bf16*  B2 = (bf16*)(ws + 117760000ULL);    // praw2 -> (floats below) -> raw1 (117.76 MB)
  // the following live INSIDE B2's span and are only valid AFTER k_s3 (praw2 dead):
  float* E1 = (float*)(ws + 117760000ULL);   // (N,256)
  float* FE = (float*)(ws + 138240000ULL);   // (N,128)
  float* LN = (float*)(ws + 148480000ULL);   // (N,128)
  float* AG = (float*)(ws + 158720000ULL);   // (N,128) classifier temp
  float* DI = (float*)(ws + 168960000ULL);   // (N) dinv
  float* DC = (float*)(ws + 169040000ULL);   // (N,160)
  int*   DG  = (int*)(ws + 182000000ULL);    // (N)
  int*   OFF = (int*)(ws + 182100000ULL);    // (N+1)
  int*   CUR = (int*)(ws + 182200000ULL);    // (N)
  int*   SRC = (int*)(ws + 182300000ULL);    // (E) ends 184,860,000
  float* ST = (float*)(ws + 235520000ULL);   // 1024 floats (outside B2)

  float* zout   = (float*)d_out;             // (N,128)
  float* recon  = (float*)d_out + 2560000;   // (N,187) — written only by k_convT3 at the end
  float* logits = (float*)d_out + 6300000;   // (N,5)

  // W2T/W3T stash inside recon region (dead space until k_convT3; last read in k_s3)
  float* W2T = recon;                        // 10240 f32 (40 KB)
  bf16*  W3T = (bf16*)(recon + 10240);       // 40960 bf16 (80 KB)

  // ---- weight prep ----
  k_wprep<<<160, 256, 0, stream>>>(ec2_w, ec3_w, W2T, W3T);

  // ---- encoder ----
  (void)hipMemsetAsync(ST, 0, 1024, stream);
  k_conv1_stats<<<NS, 256, 0, stream>>>(wav, ec1_w, ec1_b, ST);
  k_bn_finalize<<<1, 128, 0, stream>>>(ST, bn1e_g, bn1e_b, 32, 1.f / (NS * 187.f), 256);
  (void)hipMemsetAsync(ST, 0, 1024, stream);
  k_s12<<<NS, 256, 0, stream>>>(wav, ec1_w, ec1_b, ST + 256, ST + 384, W2T, ec2_b, B2, ST);
  k_bn_finalize<<<1, 128, 0, stream>>>(ST, bn2e_g, bn2e_b, 64, 1.f / (NS * 93.f), 512);
  (void)hipMemsetAsync(ST, 0, 1024, stream);
  k_s3<<<NS, 256, 0, stream>>>(B2, ST + 512, ST + 640, W3T, ec3_b, B1, ST);
  k_bn_finalize<<<1, 128, 0, stream>>>(ST, bn3e_g, bn3e_b, 128, 1.f / (NS * 46.f), 768);

  // ---- GCN CSR build (AFTER k_s3: praw2 dead, so DG/OFF/CUR/SRC inside B2 are safe) ----
  (void)hipMemsetAsync(DG, 0, NS * 4, stream);
  k_degacc_int<<<2500, 256, 0, stream>>>(edges + NE, DG);
  k_scan<<<1, 1024, 0, stream>>>(DG, OFF, CUR);
  k_dinv<<<79, 256, 0, stream>>>(DG, DI);
  k_place<<<2500, 256, 0, stream>>>(edges, edges + NE, CUR, SRC);

  // ---- encoder FCs (MFMA path) ----
  k_bnrelu<<<2048, 256, 0, stream>>>(B1, ST + 768, ST + 896);
  k_mgemm<bf16, float, true><<<dim3(2, 157), 256, 0, stream>>>(B1, efc1_w, efc1_b, E1, NS, 2944, 256);
  k_gemm<float, false, false><<<dim3(313, 2), 256, 0, stream>>>(E1, efc2_w, efc2_b, nullptr, FE, NS, 256, 128);

  // ---- GCN ----
  k_gemm<float, false, true><<<dim3(313, 2), 256, 0, stream>>>(FE, g1_w, nullptr, DI, LN, NS, 128, 128);
  k_gcn_agg<true><<<NS, 128, 0, stream>>>(OFF, SRC, LN, DI, g1_b, FE);
  k_gemm<float, false, true><<<dim3(313, 2), 256, 0, stream>>>(FE, g2_w, nullptr, DI, LN, NS, 128, 128);
  k_gcn_agg<false><<<NS, 128, 0, stream>>>(OFF, SRC, LN, DI, g2_b, zout);

  // ---- classifier ----
  k_gemm<float, true, false><<<dim3(313, 1), 256, 0, stream>>>(zout, c1_w, c1_b, nullptr, AG, NS, 128, 64);
  k_gemm<float, false, false><<<dim3(313, 1), 256, 0, stream>>>(AG, c2_w, c2_b, nullptr, logits, NS, 64, 5);

  // ---- decoder ----
  k_dcat<<<4096, 256, 0, stream>>>(zout, labels, cls_emb, DC);
  k_gemm<float, true, false><<<dim3(313, 4), 256, 0, stream>>>(DC, dfc1_w, dfc1_b, nullptr, E1, NS, 160, 256);
  k_mgemm<float, bf16, true><<<dim3(23, 157), 256, 0, stream>>>(E1, dfc2_w, dfc2_b, B1, NS, 256, 2944);
  (void)hipMemsetAsync(ST, 0, 1024, stream);
  k_convT1<<<NS, 256, 0, stream>>>(B1, dc1_w, dc1_b, B2, ST);
  k_bn_finalize<<<1, 128, 0, stream>>>(ST, bn1d_g, bn1d_b, 64, 1.f / (NS * 46.f), 256);
  (void)hipMemsetAsync(ST, 0, 1024, stream);
  k_convT2<<<NS, 256, 0, stream>>>(B2, ST + 256, ST + 384, dc2_w, dc2_b, B1, ST);
  k_bn_finalize<<<1, 128, 0, stream>>>(ST, bn2d_g, bn2d_b, 32, 1.f / (NS * 92.f), 512);
  k_convT3<<<NS, 256, 0, stream>>>(B1, ST + 512, ST + 640, dc3_w, dc3_b, recon);
}